// Round 6
// baseline (1584.304 us; speedup 1.0000x reference)
//
#include <hip/hip_runtime.h>
#include <math.h>

typedef unsigned int   u32;
typedef unsigned short u16;
typedef __attribute__((ext_vector_type(8))) short short8;
typedef __attribute__((ext_vector_type(4))) float f32x4;

#define TAUF 0.0350f
#define CAP  192

__device__ __forceinline__ u16 f2b(float f) {
  u32 u = __float_as_uint(f);
  u += 0x7fffu + ((u >> 16) & 1u);   // RNE
  return (u16)(u >> 16);
}

__device__ __forceinline__ void gload_lds16(const void* g, void* l) {
  __builtin_amdgcn_global_load_lds(
      (const __attribute__((address_space(1))) u32*)g,
      (__attribute__((address_space(3))) u32*)l, 16, 0, 0);
}

#define FMA16 \
  acc[0][0]=fmaf(a4.x,b4.x,acc[0][0]); acc[0][1]=fmaf(a4.x,b4.y,acc[0][1]); \
  acc[0][2]=fmaf(a4.x,b4.z,acc[0][2]); acc[0][3]=fmaf(a4.x,b4.w,acc[0][3]); \
  acc[1][0]=fmaf(a4.y,b4.x,acc[1][0]); acc[1][1]=fmaf(a4.y,b4.y,acc[1][1]); \
  acc[1][2]=fmaf(a4.y,b4.z,acc[1][2]); acc[1][3]=fmaf(a4.y,b4.w,acc[1][3]); \
  acc[2][0]=fmaf(a4.z,b4.x,acc[2][0]); acc[2][1]=fmaf(a4.z,b4.y,acc[2][1]); \
  acc[2][2]=fmaf(a4.z,b4.z,acc[2][2]); acc[2][3]=fmaf(a4.z,b4.w,acc[2][3]); \
  acc[3][0]=fmaf(a4.w,b4.x,acc[3][0]); acc[3][1]=fmaf(a4.w,b4.y,acc[3][1]); \
  acc[3][2]=fmaf(a4.w,b4.z,acc[3][2]); acc[3][3]=fmaf(a4.w,b4.w,acc[3][3]);

// ---------- QKV projection: fp32 C[2048,512] = A @ W[512,512] + b ----------
__global__ __launch_bounds__(256) void gemm_qkv(const float* __restrict__ x,
    const float* __restrict__ Wq, const float* __restrict__ bq,
    const float* __restrict__ Wk, const float* __restrict__ bk,
    const float* __restrict__ Wv, const float* __restrict__ bv,
    float* __restrict__ Qo, float* __restrict__ Ko, float* __restrict__ Vo)
{
  __shared__ float As[16][68];
  __shared__ float Bs[16][68];
  int z = blockIdx.z;
  const float* W    = (z == 0) ? Wq : (z == 1) ? Wk : Wv;
  const float* bias = (z == 0) ? bq : (z == 1) ? bk : bv;
  float*       out  = (z == 0) ? Qo : (z == 1) ? Ko : Vo;
  int t = threadIdx.x;
  int m0 = blockIdx.y * 64, n0 = blockIdx.x * 64;
  int tx = t & 15, ty = t >> 4;
  int am = t >> 2, ak = (t & 3) * 4;
  int bkk = t >> 4, bn = (t & 15) * 4;
  float acc[4][4] = {};
  for (int k0 = 0; k0 < 512; k0 += 16) {
    float4 fa = *(const float4*)&x[(m0 + am) * 512 + k0 + ak];
    float4 fb = *(const float4*)&W[(k0 + bkk) * 512 + n0 + bn];
    As[ak + 0][am] = fa.x; As[ak + 1][am] = fa.y;
    As[ak + 2][am] = fa.z; As[ak + 3][am] = fa.w;
    Bs[bkk][bn + 0] = fb.x; Bs[bkk][bn + 1] = fb.y;
    Bs[bkk][bn + 2] = fb.z; Bs[bkk][bn + 3] = fb.w;
    __syncthreads();
    #pragma unroll
    for (int kk = 0; kk < 16; ++kk) {
      float4 a4 = *(const float4*)&As[kk][ty * 4];
      float4 b4 = *(const float4*)&Bs[kk][tx * 4];
      FMA16
    }
    __syncthreads();
  }
  float bb0 = bias[n0+tx*4+0], bb1 = bias[n0+tx*4+1];
  float bb2 = bias[n0+tx*4+2], bb3 = bias[n0+tx*4+3];
  #pragma unroll
  for (int r = 0; r < 4; ++r) {
    float4 o = { acc[r][0] + bb0, acc[r][1] + bb1, acc[r][2] + bb2, acc[r][3] + bb3 };
    *(float4*)&out[(m0 + ty*4 + r) * 512 + n0 + tx*4] = o;
  }
}

// ---------- output projection: fp32 out = A[2048,512] @ Wo + bo ----------
__global__ __launch_bounds__(256) void gemm_out_k(const float* __restrict__ A,
    const float* __restrict__ W, const float* __restrict__ bias, float* __restrict__ out)
{
  __shared__ float As[16][68];
  __shared__ float Bs[16][68];
  int t = threadIdx.x;
  int m0 = blockIdx.y * 64, n0 = blockIdx.x * 64;
  int tx = t & 15, ty = t >> 4;
  int am = t >> 2, ak = (t & 3) * 4;
  int bkk = t >> 4, bn = (t & 15) * 4;
  float acc[4][4] = {};
  for (int k0 = 0; k0 < 512; k0 += 16) {
    float4 fa = *(const float4*)&A[(m0 + am) * 512 + k0 + ak];
    float4 fb = *(const float4*)&W[(k0 + bkk) * 512 + n0 + bn];
    As[ak + 0][am] = fa.x; As[ak + 1][am] = fa.y;
    As[ak + 2][am] = fa.z; As[ak + 3][am] = fa.w;
    Bs[bkk][bn + 0] = fb.x; Bs[bkk][bn + 1] = fb.y;
    Bs[bkk][bn + 2] = fb.z; Bs[bkk][bn + 3] = fb.w;
    __syncthreads();
    #pragma unroll
    for (int kk = 0; kk < 16; ++kk) {
      float4 a4 = *(const float4*)&As[kk][ty * 4];
      float4 b4 = *(const float4*)&Bs[kk][tx * 4];
      FMA16
    }
    __syncthreads();
  }
  float bb0 = bias[n0+tx*4+0], bb1 = bias[n0+tx*4+1];
  float bb2 = bias[n0+tx*4+2], bb3 = bias[n0+tx*4+3];
  #pragma unroll
  for (int r = 0; r < 4; ++r) {
    float4 o = { acc[r][0] + bb0, acc[r][1] + bb1, acc[r][2] + bb2, acc[r][3] + bb3 };
    *(float4*)&out[(m0 + ty*4 + r) * 512 + n0 + tx*4] = o;
  }
}

// ---------- memory-path q̂ in fp64: QM64/QM32 [16384][64], pre-scaled by 1/((||q||+1e-8)*8) ----------
__global__ __launch_bounds__(256) void qmem64_kernel(const float* __restrict__ x,
    const float* __restrict__ Wq, const float* __restrict__ bq,
    double* __restrict__ QM64, float* __restrict__ QM32)
{
  __shared__ float xs[32][68];
  __shared__ float wsh[64][68];
  __shared__ double psum[32][8];
  __shared__ double scal[32];
  int t = threadIdx.x;
  int qq0 = blockIdx.x * 32;                  // 32 consecutive queries: same (b1,h1), s=s0..s0+31
  int b1 = qq0 >> 13, h1 = (qq0 >> 10) & 7, s0 = qq0 & 1023;
  int i = h1 * 2 + b1;                        // torch-reshape scramble
  int batch = i >> 3, col0 = (i & 7) * 64;
  int row = t >> 3, cg = (t & 7) * 8;
  double acc[8] = {};
  for (int k0 = 0; k0 < 512; k0 += 64) {
    #pragma unroll
    for (int j = 0; j < 2; ++j) {
      int idx = t + j * 256;
      int r = idx >> 4, c = (idx & 15) * 4;
      float4 f = *(const float4*)&x[(batch * 1024 + s0 + r) * 512 + k0 + c];
      xs[r][c+0] = f.x; xs[r][c+1] = f.y; xs[r][c+2] = f.z; xs[r][c+3] = f.w;
    }
    #pragma unroll
    for (int j = 0; j < 4; ++j) {
      int idx = t + j * 256;
      int r = idx >> 4, c = (idx & 15) * 4;
      float4 f = *(const float4*)&Wq[(k0 + r) * 512 + col0 + c];
      wsh[r][c+0] = f.x; wsh[r][c+1] = f.y; wsh[r][c+2] = f.z; wsh[r][c+3] = f.w;
    }
    __syncthreads();
    for (int kk = 0; kk < 64; ++kk) {
      double xv = (double)xs[row][kk];
      #pragma unroll
      for (int j = 0; j < 8; ++j) acc[j] = fma(xv, (double)wsh[kk][cg + j], acc[j]);
    }
    __syncthreads();
  }
  #pragma unroll
  for (int j = 0; j < 8; ++j) acc[j] += (double)bq[col0 + cg + j];
  double ps = 0.0;
  #pragma unroll
  for (int j = 0; j < 8; ++j) ps = fma(acc[j], acc[j], ps);
  psum[row][t & 7] = ps;
  __syncthreads();
  if (t < 32) {
    double s = 0.0;
    #pragma unroll
    for (int j = 0; j < 8; ++j) s += psum[t][j];
    scal[t] = 1.0 / ((sqrt(s) + 1e-8) * 8.0);
  }
  __syncthreads();
  double sc = scal[row];
  #pragma unroll
  for (int j = 0; j < 8; ++j) {
    double v = acc[j] * sc;
    QM64[(qq0 + row) * 64 + cg + j] = v;
    QM32[(qq0 + row) * 64 + cg + j] = (float)v;
  }
}

// ---------- per-memory fp64 norm: kinv64 + raw-dot threshold tau32 = TAU*(||K||+1e-8) ----------
__global__ __launch_bounds__(256) void kprep_kernel(const float* __restrict__ Km,
    double* __restrict__ kinv64, float* __restrict__ tau32)
{
  int idx = blockIdx.x * 256 + threadIdx.x;   // 65536
  const float* p = Km + idx * 64;
  double s = 0.0;
  #pragma unroll
  for (int j = 0; j < 16; ++j) {
    float4 f = *(const float4*)&p[j * 4];
    double a = f.x, b = f.y, c = f.z, d = f.w;
    s = fma(a, a, s); s = fma(b, b, s); s = fma(c, c, s); s = fma(d, d, s);
  }
  double nrm = sqrt(s) + 1e-8;
  kinv64[idx] = 1.0 / nrm;
  tau32[idx] = (float)((double)TAUF * nrm);
}

// ---------- Km -> bf16 (once): KB16[65536*64] ----------
__global__ __launch_bounds__(256) void kcvt_kernel(const float* __restrict__ Km,
                                                   u32* __restrict__ KB)
{
  int o = blockIdx.x * 256 + threadIdx.x;     // 524288 threads x 8 floats
  float4 f0 = *(const float4*)&Km[o * 8];
  float4 f1 = *(const float4*)&Km[o * 8 + 4];
  uint4 u;
  u.x = ((u32)f2b(f0.y) << 16) | f2b(f0.x);
  u.y = ((u32)f2b(f0.w) << 16) | f2b(f0.z);
  u.z = ((u32)f2b(f1.y) << 16) | f2b(f1.x);
  u.w = ((u32)f2b(f1.w) << 16) | f2b(f1.z);
  *(uint4*)&KB[o * 4] = u;
}

// ---------- causal attention: 4 query rows per block, batch-head i = blockIdx.y ----------
__global__ __launch_bounds__(256) void attn_kernel(const float* __restrict__ Qb,
    const float* __restrict__ Kb, const float* __restrict__ Vb, float* __restrict__ attn)
{
  __shared__ float qs[4][64];
  __shared__ float Kc[64][65];
  __shared__ float sl[4][1024];
  int bi = blockIdx.y;               // i = borig*8 + horig
  int sq0 = blockIdx.x * 4;
  int borig = bi >> 3, horig = bi & 7;
  int t = threadIdx.x;
  int base = borig * 524288 + horig * 64;
  int w = t >> 6, l = t & 63;
  qs[w][l] = Qb[base + (sq0 + w) * 512 + l];
  __syncthreads();
  int nk = sq0 + 4;
  for (int k0 = 0; k0 < nk; k0 += 64) {
    #pragma unroll
    for (int j = 0; j < 4; ++j) {
      int idx = t + j * 256;
      int key = idx >> 4, f = idx & 15;
      if (k0 + key < nk) {
        float4 kv = *(const float4*)&Kb[base + (k0 + key) * 512 + f * 4];
        Kc[key][f*4+0] = kv.x; Kc[key][f*4+1] = kv.y;
        Kc[key][f*4+2] = kv.z; Kc[key][f*4+3] = kv.w;
      }
    }
    __syncthreads();
    int key = k0 + l;
    if (key <= sq0 + w) {
      float dv = 0.f;
      #pragma unroll
      for (int d = 0; d < 64; ++d) dv = fmaf(qs[w][d], Kc[l][d], dv);
      sl[w][key] = dv * 0.125f;
    }
    __syncthreads();
  }
  int nkr = sq0 + w + 1;
  float mx = -__builtin_inff();
  for (int k = l; k < nkr; k += 64) mx = fmaxf(mx, sl[w][k]);
  #pragma unroll
  for (int msk = 32; msk >= 1; msk >>= 1) mx = fmaxf(mx, __shfl_xor(mx, msk));
  float sum = 0.f;
  for (int k = l; k < nkr; k += 64) { float p = __expf(sl[w][k] - mx); sl[w][k] = p; sum += p; }
  #pragma unroll
  for (int msk = 32; msk >= 1; msk >>= 1) sum += __shfl_xor(sum, msk);
  float inv = 1.0f / sum;
  __syncthreads();
  float acc = 0.f;
  const float* vp = &Vb[base + l];
  #pragma unroll 4
  for (int k = 0; k < nkr; ++k) acc = fmaf(sl[w][k], vp[k * 512], acc);
  attn[(bi * 1024 + sq0 + w) * 64 + l] = acc * inv;
}

// ---------- KNN filter: bf16 MFMA raw dots vs per-memory tau -> global candidate pool ----------
// grid (512 qtiles, 2 mem-shards); dbuf global_load_lds staging with XOR granule swizzle
__global__ __launch_bounds__(256) void knnA_kernel(
    const float* __restrict__ QM32, const u16* __restrict__ KB16,
    const float* __restrict__ tau32, u32* __restrict__ pcnt, u16* __restrict__ pidx)
{
  __shared__ u16   Kc[2][128 * 64];
  __shared__ float tauc[2][128];
  int t = threadIdx.x;
  int l = t & 63, w = t >> 6;
  int lane15 = l & 15, quad = l >> 4;
  int qq0 = blockIdx.x * 32;
  int h2 = qq0 >> 11;
  int mbase = blockIdx.y * 4096;             // shard
  const u16* KBh = KB16 + (size_t)(h2 * 8192) * 64;
  const float* tauh = tau32 + h2 * 8192;
  // A-frags: q̂ rows (bf16), resident in VGPRs
  short8 afr[2][2];
  #pragma unroll
  for (int qt = 0; qt < 2; ++qt) {
    int q = qq0 + qt * 16 + lane15;
    #pragma unroll
    for (int kh = 0; kh < 2; ++kh) {
      const float* qp = &QM32[q * 64 + kh * 32 + quad * 8];
      float4 fa = *(const float4*)qp;
      float4 fb = *(const float4*)(qp + 4);
      short8 a;
      a[0]=(short)f2b(fa.x); a[1]=(short)f2b(fa.y); a[2]=(short)f2b(fa.z); a[3]=(short)f2b(fa.w);
      a[4]=(short)f2b(fb.x); a[5]=(short)f2b(fb.y); a[6]=(short)f2b(fb.z); a[7]=(short)f2b(fb.w);
      afr[qt][kh] = a;
    }
  }
  // --- staging helper (async): chunk c of this shard into buffer buf ---
  #define STAGE(buf, c) do { \
    int m0s = mbase + (c) * 128; \
    _Pragma("unroll") \
    for (int i2 = 0; i2 < 4; ++i2) { \
      int slot = i2 * 256 + t; \
      int mm = slot >> 3, gs = slot & 7; \
      int gsrc = gs ^ (mm & 7); \
      gload_lds16(KBh + (size_t)(m0s + mm) * 64 + gsrc * 8, \
                  &Kc[buf][(size_t)(i2 * 256 + (t & ~63)) * 8]); \
    } \
    if (t < 32) gload_lds16(&tauh[m0s + t * 4], &tauc[buf][0]); \
  } while (0)

  STAGE(0, 0);
  __syncthreads();
  for (int c = 0; c < 32; ++c) {
    int cur = c & 1;
    if (c + 1 < 32) STAGE(cur ^ 1, c + 1);
    #pragma unroll
    for (int mi = 0; mi < 2; ++mi) {
      int mt = 2 * w + mi;
      int m = mt * 16 + lane15;
      float tau_m = tauc[cur][m];
      short8 b0 = *(const short8*)&Kc[cur][(m * 8 + (quad       ^ (m & 7))) * 8];
      short8 b1 = *(const short8*)&Kc[cur][(m * 8 + ((4 + quad) ^ (m & 7))) * 8];
      int m_g = mbase + c * 128 + m;
      #pragma unroll
      for (int qt = 0; qt < 2; ++qt) {
        f32x4 z = {0.f, 0.f, 0.f, 0.f};
        z = __builtin_amdgcn_mfma_f32_16x16x32_bf16(afr[qt][0], b0, z, 0, 0, 0);
        z = __builtin_amdgcn_mfma_f32_16x16x32_bf16(afr[qt][1], b1, z, 0, 0, 0);
        #pragma unroll
        for (int r4 = 0; r4 < 4; ++r4) {
          if (z[r4] > tau_m) {                       // raw dot vs TAU*||K_m||
            int ql = qq0 + qt * 16 + quad * 4 + r4;  // D: row=quad*4+reg (query), col=lane15 (mem)
            u32 p = atomicAdd(&pcnt[ql], 1u);
            if (p < CAP) pidx[(size_t)ql * CAP + p] = (u16)m_g;
          }
        }
      }
    }
    __syncthreads();
  }
  #undef STAGE
}

// ---------- KNN select: fp64 rescore pool -> exact top-33 -> soft-blend -> fp64 V-sum ----------
__global__ __launch_bounds__(256) void knnB_kernel(
    const u32* __restrict__ pcnt, const u16* __restrict__ pidx,
    const double* __restrict__ QM64, const float* __restrict__ Km,
    const float* __restrict__ Vm, const double* __restrict__ kinv64,
    float* __restrict__ wt)
{
  __shared__ double pool_val[32][CAP];
  __shared__ u16    pool_i[32][CAP];
  __shared__ int    ncnt[32];
  int t = threadIdx.x;
  int qq0 = blockIdx.x * 32;
  int h2 = qq0 >> 11;
  if (t < 32) ncnt[t] = min((int)pcnt[qq0 + t], CAP);
  __syncthreads();
  for (int slot = t; slot < 32 * CAP; slot += 256) {
    int q = slot / CAP, j = slot - q * CAP;
    int n = ncnt[q];
    if (j < n) {
      int id = pidx[(size_t)(qq0 + q) * CAP + j];
      pool_i[q][j] = (u16)id;
      const double* qv = &QM64[(qq0 + q) * 64];
      const float*  kr = &Km[(size_t)(h2 * 8192 + id) * 64];
      double dot = 0.0;
      #pragma unroll
      for (int d = 0; d < 64; ++d) dot = fma(qv[d], (double)kr[d], dot);
      pool_val[q][j] = dot * kinv64[h2 * 8192 + id];
    } else if (j < 34) {
      pool_val[q][j] = -1e30;
      pool_i[q][j] = 0;
    }
  }
  __syncthreads();
  if (t < 32) {
    int n = ncnt[t];
    int nscan = n < 34 ? 34 : n;
    for (int sel = 0; sel < 33; ++sel) {
      double best = -1e300; int bid = 0x7fffffff; int bj = sel;
      for (int j = sel; j < nscan; ++j) {
        double v = pool_val[t][j]; int id = pool_i[t][j];
        if (v > best || (v == best && id < bid)) { best = v; bid = id; bj = j; }
      }
      double tv = pool_val[t][sel]; int ti = pool_i[t][sel];
      pool_val[t][sel] = pool_val[t][bj]; pool_i[t][sel] = pool_i[t][bj];
      pool_val[t][bj] = tv; pool_i[t][bj] = (u16)ti;
    }
    double g = pool_val[t][31] - pool_val[t][32];
    double lam = 0.5 * erfc(g * 471404.52);   // 1/(sqrt(2)*1.5e-6)
    pool_val[t][31] *= (1.0 - lam);
    pool_val[t][32] *= lam;
  }
  __syncthreads();
  int w = t >> 6, l = t & 63;
  const float* Vmh = Vm + (size_t)h2 * 524288;
  for (int qi = 0; qi < 8; ++qi) {
    int q = w * 8 + qi;
    double acc = 0.0;
    #pragma unroll 3
    for (int j = 0; j < 33; ++j) {
      double v = pool_val[q][j];
      int id = pool_i[q][j];
      if (v > -1e29) acc = fma(v, (double)Vmh[id * 64 + l], acc);
    }
    wt[(qq0 + q) * 64 + l] = (float)acc;
  }
}

// ---------- gate combine -> [2048, 512] fp32 ----------
__global__ __launch_bounds__(256) void combine_kernel(const float* __restrict__ attn,
    const float* __restrict__ wt, const float* __restrict__ gate, float* __restrict__ comb)
{
  int tid = blockIdx.x * 256 + threadIdx.x;     // < 1048576
  int r = tid >> 9, c = tid & 511;
  int ho = c >> 6, dk = c & 63;
  int bo = r >> 10, s = r & 1023;
  float g = 1.0f / (1.0f + __expf(-gate[ho]));
  float wv = wt[(ho * 2048 + r) * 64 + dk];                  // weighted[ho][bo*1024+s][dk]
  float av = attn[((ho * 2 + bo) * 1024 + s) * 64 + dk];     // attn_out[i_att=ho*2+bo]
  comb[tid] = g * wv + (1.0f - g) * av;
}

extern "C" void kernel_launch(void* const* d_in, const int* in_sizes, int n_in,
                              void* d_out, int out_size, void* d_ws, size_t ws_size,
                              hipStream_t stream) {
  const float* x    = (const float*)d_in[0];
  const float* Wq   = (const float*)d_in[1];
  const float* bq   = (const float*)d_in[2];
  const float* Wk   = (const float*)d_in[3];
  const float* bk   = (const float*)d_in[4];
  const float* Wv   = (const float*)d_in[5];
  const float* bv   = (const float*)d_in[6];
  const float* Wo   = (const float*)d_in[7];
  const float* bo   = (const float*)d_in[8];
  const float* Km   = (const float*)d_in[9];
  const float* Vm   = (const float*)d_in[10];
  const float* gate = (const float*)d_in[11];
  float* out = (float*)d_out;
  float* ws = (float*)d_ws;
  // layout (floats). KB16 overlays WT+COMB; pool overlays Q/K (disjoint lifetimes).
  float*  Q      = ws;                         // [0, 1048576)
  float*  K      = ws + 1048576;               // [1048576, 2097152)
  float*  V      = ws + 2097152;               // [2097152, 3145728)
  float*  ATT    = ws + 3145728;               // [3145728, 4194304)
  float*  WT     = ws + 4194304;               // [4194304, 5242880)  (after knnA)
  float*  COMB   = ws + 5242880;               // [5242880, 6291456)  (after knnB)
  u16*    KB16   = (u16*)(ws + 4194304);       // 8.39 MB, lifetime kcvt..knnA
  float*  QM32   = ws + 6291456;               // 1048576
  float*  TAU32  = ws + 7340032;               // 65536
  double* QM64   = (double*)(ws + 7405568);    // 1048576 doubles
  double* KINV64 = (double*)(ws + 9502720);    // 65536 doubles
  u32*    PCNT   = (u32*)ws;                   // 16384 u32, lifetime post-attn (over Q)
  u16*    PIDX   = (u16*)(ws + 16384);         // 16384*CAP u16 (over Q/K)
  gemm_qkv<<<dim3(8, 32, 3), 256, 0, stream>>>(x, Wq, bq, Wk, bk, Wv, bv, Q, K, V);
  qmem64_kernel<<<dim3(512), 256, 0, stream>>>(x, Wq, bq, QM64, QM32);
  kprep_kernel<<<dim3(256), 256, 0, stream>>>(Km, KINV64, TAU32);
  kcvt_kernel<<<dim3(2048), 256, 0, stream>>>(Km, (u32*)KB16);
  attn_kernel<<<dim3(256, 16), 256, 0, stream>>>(Q, K, V, ATT);
  hipMemsetAsync(PCNT, 0, 16384 * sizeof(u32), stream);
  knnA_kernel<<<dim3(512, 2), 256, 0, stream>>>(QM32, KB16, TAU32, PCNT, PIDX);
  knnB_kernel<<<dim3(512), 256, 0, stream>>>(PCNT, PIDX, QM64, Km, Vm, KINV64, WT);
  combine_kernel<<<dim3(4096), 256, 0, stream>>>(ATT, WT, gate, COMB);
  gemm_out_k<<<dim3(8, 32), 256, 0, stream>>>(COMB, Wo, bo, out);
}

// Round 7
// 954.834 us; speedup vs baseline: 1.6592x; 1.6592x over previous
//
#include <hip/hip_runtime.h>
#include <math.h>

typedef unsigned int   u32;
typedef unsigned short u16;
typedef __attribute__((ext_vector_type(8))) short short8;
typedef __attribute__((ext_vector_type(4))) float f32x4;

#define TAUF 0.0350f
#define CAP  192

__device__ __forceinline__ u16 f2b(float f) {
  u32 u = __float_as_uint(f);
  u += 0x7fffu + ((u >> 16) & 1u);   // RNE
  return (u16)(u >> 16);
}

__device__ __forceinline__ void gload_lds16(const void* g, void* l) {
  __builtin_amdgcn_global_load_lds(
      (const __attribute__((address_space(1))) u32*)g,
      (__attribute__((address_space(3))) u32*)l, 16, 0, 0);
}

#define FMA16 \
  acc[0][0]=fmaf(a4.x,b4.x,acc[0][0]); acc[0][1]=fmaf(a4.x,b4.y,acc[0][1]); \
  acc[0][2]=fmaf(a4.x,b4.z,acc[0][2]); acc[0][3]=fmaf(a4.x,b4.w,acc[0][3]); \
  acc[1][0]=fmaf(a4.y,b4.x,acc[1][0]); acc[1][1]=fmaf(a4.y,b4.y,acc[1][1]); \
  acc[1][2]=fmaf(a4.y,b4.z,acc[1][2]); acc[1][3]=fmaf(a4.y,b4.w,acc[1][3]); \
  acc[2][0]=fmaf(a4.z,b4.x,acc[2][0]); acc[2][1]=fmaf(a4.z,b4.y,acc[2][1]); \
  acc[2][2]=fmaf(a4.z,b4.z,acc[2][2]); acc[2][3]=fmaf(a4.z,b4.w,acc[2][3]); \
  acc[3][0]=fmaf(a4.w,b4.x,acc[3][0]); acc[3][1]=fmaf(a4.w,b4.y,acc[3][1]); \
  acc[3][2]=fmaf(a4.w,b4.z,acc[3][2]); acc[3][3]=fmaf(a4.w,b4.w,acc[3][3]);

// ---------- QKV projection: fp32 C[2048,512] = A @ W[512,512] + b ----------
__global__ __launch_bounds__(256) void gemm_qkv(const float* __restrict__ x,
    const float* __restrict__ Wq, const float* __restrict__ bq,
    const float* __restrict__ Wk, const float* __restrict__ bk,
    const float* __restrict__ Wv, const float* __restrict__ bv,
    float* __restrict__ Qo, float* __restrict__ Ko, float* __restrict__ Vo)
{
  __shared__ float As[16][68];
  __shared__ float Bs[16][68];
  int z = blockIdx.z;
  const float* W    = (z == 0) ? Wq : (z == 1) ? Wk : Wv;
  const float* bias = (z == 0) ? bq : (z == 1) ? bk : bv;
  float*       out  = (z == 0) ? Qo : (z == 1) ? Ko : Vo;
  int t = threadIdx.x;
  int m0 = blockIdx.y * 64, n0 = blockIdx.x * 64;
  int tx = t & 15, ty = t >> 4;
  int am = t >> 2, ak = (t & 3) * 4;
  int bkk = t >> 4, bn = (t & 15) * 4;
  float acc[4][4] = {};
  for (int k0 = 0; k0 < 512; k0 += 16) {
    float4 fa = *(const float4*)&x[(m0 + am) * 512 + k0 + ak];
    float4 fb = *(const float4*)&W[(k0 + bkk) * 512 + n0 + bn];
    As[ak + 0][am] = fa.x; As[ak + 1][am] = fa.y;
    As[ak + 2][am] = fa.z; As[ak + 3][am] = fa.w;
    Bs[bkk][bn + 0] = fb.x; Bs[bkk][bn + 1] = fb.y;
    Bs[bkk][bn + 2] = fb.z; Bs[bkk][bn + 3] = fb.w;
    __syncthreads();
    #pragma unroll
    for (int kk = 0; kk < 16; ++kk) {
      float4 a4 = *(const float4*)&As[kk][ty * 4];
      float4 b4 = *(const float4*)&Bs[kk][tx * 4];
      FMA16
    }
    __syncthreads();
  }
  float bb0 = bias[n0+tx*4+0], bb1 = bias[n0+tx*4+1];
  float bb2 = bias[n0+tx*4+2], bb3 = bias[n0+tx*4+3];
  #pragma unroll
  for (int r = 0; r < 4; ++r) {
    float4 o = { acc[r][0] + bb0, acc[r][1] + bb1, acc[r][2] + bb2, acc[r][3] + bb3 };
    *(float4*)&out[(m0 + ty*4 + r) * 512 + n0 + tx*4] = o;
  }
}

// ---------- output projection: fp32 out = A[2048,512] @ Wo + bo ----------
__global__ __launch_bounds__(256) void gemm_out_k(const float* __restrict__ A,
    const float* __restrict__ W, const float* __restrict__ bias, float* __restrict__ out)
{
  __shared__ float As[16][68];
  __shared__ float Bs[16][68];
  int t = threadIdx.x;
  int m0 = blockIdx.y * 64, n0 = blockIdx.x * 64;
  int tx = t & 15, ty = t >> 4;
  int am = t >> 2, ak = (t & 3) * 4;
  int bkk = t >> 4, bn = (t & 15) * 4;
  float acc[4][4] = {};
  for (int k0 = 0; k0 < 512; k0 += 16) {
    float4 fa = *(const float4*)&A[(m0 + am) * 512 + k0 + ak];
    float4 fb = *(const float4*)&W[(k0 + bkk) * 512 + n0 + bn];
    As[ak + 0][am] = fa.x; As[ak + 1][am] = fa.y;
    As[ak + 2][am] = fa.z; As[ak + 3][am] = fa.w;
    Bs[bkk][bn + 0] = fb.x; Bs[bkk][bn + 1] = fb.y;
    Bs[bkk][bn + 2] = fb.z; Bs[bkk][bn + 3] = fb.w;
    __syncthreads();
    #pragma unroll
    for (int kk = 0; kk < 16; ++kk) {
      float4 a4 = *(const float4*)&As[kk][ty * 4];
      float4 b4 = *(const float4*)&Bs[kk][tx * 4];
      FMA16
    }
    __syncthreads();
  }
  float bb0 = bias[n0+tx*4+0], bb1 = bias[n0+tx*4+1];
  float bb2 = bias[n0+tx*4+2], bb3 = bias[n0+tx*4+3];
  #pragma unroll
  for (int r = 0; r < 4; ++r) {
    float4 o = { acc[r][0] + bb0, acc[r][1] + bb1, acc[r][2] + bb2, acc[r][3] + bb3 };
    *(float4*)&out[(m0 + ty*4 + r) * 512 + n0 + tx*4] = o;
  }
}

// ---------- memory-path q̂ in fp64: QM64/QM32 [16384][64], pre-scaled by 1/((||q||+1e-8)*8) ----------
__global__ __launch_bounds__(256) void qmem64_kernel(const float* __restrict__ x,
    const float* __restrict__ Wq, const float* __restrict__ bq,
    double* __restrict__ QM64, float* __restrict__ QM32)
{
  __shared__ float xs[32][68];
  __shared__ float wsh[64][68];
  __shared__ double psum[32][8];
  __shared__ double scal[32];
  int t = threadIdx.x;
  int qq0 = blockIdx.x * 32;                  // 32 consecutive queries: same (b1,h1), s=s0..s0+31
  int b1 = qq0 >> 13, h1 = (qq0 >> 10) & 7, s0 = qq0 & 1023;
  int i = h1 * 2 + b1;                        // torch-reshape scramble
  int batch = i >> 3, col0 = (i & 7) * 64;
  int row = t >> 3, cg = (t & 7) * 8;
  double acc[8] = {};
  for (int k0 = 0; k0 < 512; k0 += 64) {
    #pragma unroll
    for (int j = 0; j < 2; ++j) {
      int idx = t + j * 256;
      int r = idx >> 4, c = (idx & 15) * 4;
      float4 f = *(const float4*)&x[(batch * 1024 + s0 + r) * 512 + k0 + c];
      xs[r][c+0] = f.x; xs[r][c+1] = f.y; xs[r][c+2] = f.z; xs[r][c+3] = f.w;
    }
    #pragma unroll
    for (int j = 0; j < 4; ++j) {
      int idx = t + j * 256;
      int r = idx >> 4, c = (idx & 15) * 4;
      float4 f = *(const float4*)&Wq[(k0 + r) * 512 + col0 + c];
      wsh[r][c+0] = f.x; wsh[r][c+1] = f.y; wsh[r][c+2] = f.z; wsh[r][c+3] = f.w;
    }
    __syncthreads();
    for (int kk = 0; kk < 64; ++kk) {
      double xv = (double)xs[row][kk];
      #pragma unroll
      for (int j = 0; j < 8; ++j) acc[j] = fma(xv, (double)wsh[kk][cg + j], acc[j]);
    }
    __syncthreads();
  }
  #pragma unroll
  for (int j = 0; j < 8; ++j) acc[j] += (double)bq[col0 + cg + j];
  double ps = 0.0;
  #pragma unroll
  for (int j = 0; j < 8; ++j) ps = fma(acc[j], acc[j], ps);
  psum[row][t & 7] = ps;
  __syncthreads();
  if (t < 32) {
    double s = 0.0;
    #pragma unroll
    for (int j = 0; j < 8; ++j) s += psum[t][j];
    scal[t] = 1.0 / ((sqrt(s) + 1e-8) * 8.0);
  }
  __syncthreads();
  double sc = scal[row];
  #pragma unroll
  for (int j = 0; j < 8; ++j) {
    double v = acc[j] * sc;
    QM64[(qq0 + row) * 64 + cg + j] = v;
    QM32[(qq0 + row) * 64 + cg + j] = (float)v;
  }
}

// ---------- per-memory fp64 norm: kinv64 + raw-dot threshold tau32 = TAU*(||K||+1e-8) ----------
__global__ __launch_bounds__(256) void kprep_kernel(const float* __restrict__ Km,
    double* __restrict__ kinv64, float* __restrict__ tau32)
{
  int idx = blockIdx.x * 256 + threadIdx.x;   // 65536
  const float* p = Km + idx * 64;
  double s = 0.0;
  #pragma unroll
  for (int j = 0; j < 16; ++j) {
    float4 f = *(const float4*)&p[j * 4];
    double a = f.x, b = f.y, c = f.z, d = f.w;
    s = fma(a, a, s); s = fma(b, b, s); s = fma(c, c, s); s = fma(d, d, s);
  }
  double nrm = sqrt(s) + 1e-8;
  kinv64[idx] = 1.0 / nrm;
  tau32[idx] = (float)((double)TAUF * nrm);
}

// ---------- Km -> bf16 (once): KB16[65536*64] ----------
__global__ __launch_bounds__(256) void kcvt_kernel(const float* __restrict__ Km,
                                                   u32* __restrict__ KB)
{
  int o = blockIdx.x * 256 + threadIdx.x;     // 524288 threads x 8 floats
  float4 f0 = *(const float4*)&Km[o * 8];
  float4 f1 = *(const float4*)&Km[o * 8 + 4];
  uint4 u;
  u.x = ((u32)f2b(f0.y) << 16) | f2b(f0.x);
  u.y = ((u32)f2b(f0.w) << 16) | f2b(f0.z);
  u.z = ((u32)f2b(f1.y) << 16) | f2b(f1.x);
  u.w = ((u32)f2b(f1.w) << 16) | f2b(f1.z);
  *(uint4*)&KB[o * 4] = u;
}

// ---------- causal attention: 4 query rows per block, batch-head i = blockIdx.y ----------
__global__ __launch_bounds__(256) void attn_kernel(const float* __restrict__ Qb,
    const float* __restrict__ Kb, const float* __restrict__ Vb, float* __restrict__ attn)
{
  __shared__ float qs[4][64];
  __shared__ float Kc[64][65];
  __shared__ float sl[4][1024];
  int bi = blockIdx.y;               // i = borig*8 + horig
  int sq0 = blockIdx.x * 4;
  int borig = bi >> 3, horig = bi & 7;
  int t = threadIdx.x;
  int base = borig * 524288 + horig * 64;
  int w = t >> 6, l = t & 63;
  qs[w][l] = Qb[base + (sq0 + w) * 512 + l];
  __syncthreads();
  int nk = sq0 + 4;
  for (int k0 = 0; k0 < nk; k0 += 64) {
    #pragma unroll
    for (int j = 0; j < 4; ++j) {
      int idx = t + j * 256;
      int key = idx >> 4, f = idx & 15;
      if (k0 + key < nk) {
        float4 kv = *(const float4*)&Kb[base + (k0 + key) * 512 + f * 4];
        Kc[key][f*4+0] = kv.x; Kc[key][f*4+1] = kv.y;
        Kc[key][f*4+2] = kv.z; Kc[key][f*4+3] = kv.w;
      }
    }
    __syncthreads();
    int key = k0 + l;
    if (key <= sq0 + w) {
      float dv = 0.f;
      #pragma unroll
      for (int d = 0; d < 64; ++d) dv = fmaf(qs[w][d], Kc[l][d], dv);
      sl[w][key] = dv * 0.125f;
    }
    __syncthreads();
  }
  int nkr = sq0 + w + 1;
  float mx = -__builtin_inff();
  for (int k = l; k < nkr; k += 64) mx = fmaxf(mx, sl[w][k]);
  #pragma unroll
  for (int msk = 32; msk >= 1; msk >>= 1) mx = fmaxf(mx, __shfl_xor(mx, msk));
  float sum = 0.f;
  for (int k = l; k < nkr; k += 64) { float p = __expf(sl[w][k] - mx); sl[w][k] = p; sum += p; }
  #pragma unroll
  for (int msk = 32; msk >= 1; msk >>= 1) sum += __shfl_xor(sum, msk);
  float inv = 1.0f / sum;
  __syncthreads();
  float acc = 0.f;
  const float* vp = &Vb[base + l];
  #pragma unroll 4
  for (int k = 0; k < nkr; ++k) acc = fmaf(sl[w][k], vp[k * 512], acc);
  attn[(bi * 1024 + sq0 + w) * 64 + l] = acc * inv;
}

// ---------- KNN filter: bf16 MFMA raw dots vs per-memory tau -> global candidate pool ----------
// grid (512 qtiles, 2 mem-shards); dbuf global_load_lds staging with XOR granule swizzle
__global__ __launch_bounds__(256) void knnA_kernel(
    const float* __restrict__ QM32, const u16* __restrict__ KB16,
    const float* __restrict__ tau32, u32* __restrict__ pcnt, u16* __restrict__ pidx)
{
  __shared__ u16   Kc[2][128 * 64];
  __shared__ float tauc[2][128];
  int t = threadIdx.x;
  int l = t & 63, w = t >> 6;
  int lane15 = l & 15, quad = l >> 4;
  int qq0 = blockIdx.x * 32;
  int h2 = qq0 >> 11;
  int mbase = blockIdx.y * 4096;             // shard
  const u16* KBh = KB16 + (size_t)(h2 * 8192) * 64;
  const float* tauh = tau32 + h2 * 8192;
  // A-frags: q̂ rows (bf16), resident in VGPRs
  short8 afr[2][2];
  #pragma unroll
  for (int qt = 0; qt < 2; ++qt) {
    int q = qq0 + qt * 16 + lane15;
    #pragma unroll
    for (int kh = 0; kh < 2; ++kh) {
      const float* qp = &QM32[q * 64 + kh * 32 + quad * 8];
      float4 fa = *(const float4*)qp;
      float4 fb = *(const float4*)(qp + 4);
      short8 a;
      a[0]=(short)f2b(fa.x); a[1]=(short)f2b(fa.y); a[2]=(short)f2b(fa.z); a[3]=(short)f2b(fa.w);
      a[4]=(short)f2b(fb.x); a[5]=(short)f2b(fb.y); a[6]=(short)f2b(fb.z); a[7]=(short)f2b(fb.w);
      afr[qt][kh] = a;
    }
  }
  // --- staging helper (async): chunk c of this shard into buffer buf ---
  #define STAGE(buf, c) do { \
    int m0s = mbase + (c) * 128; \
    _Pragma("unroll") \
    for (int i2 = 0; i2 < 4; ++i2) { \
      int slot = i2 * 256 + t; \
      int mm = slot >> 3, gs = slot & 7; \
      int gsrc = gs ^ (mm & 7); \
      gload_lds16(KBh + (size_t)(m0s + mm) * 64 + gsrc * 8, \
                  &Kc[buf][(size_t)(i2 * 256 + (t & ~63)) * 8]); \
    } \
    if (t < 32) gload_lds16(&tauh[m0s + t * 4], &tauc[buf][0]); \
  } while (0)

  STAGE(0, 0);
  __syncthreads();
  for (int c = 0; c < 32; ++c) {
    int cur = c & 1;
    if (c + 1 < 32) STAGE(cur ^ 1, c + 1);
    #pragma unroll
    for (int mi = 0; mi < 2; ++mi) {
      int mt = 2 * w + mi;
      int m = mt * 16 + lane15;
      float tau_m = tauc[cur][m];
      short8 b0 = *(const short8*)&Kc[cur][(m * 8 + (quad       ^ (m & 7))) * 8];
      short8 b1 = *(const short8*)&Kc[cur][(m * 8 + ((4 + quad) ^ (m & 7))) * 8];
      int m_g = mbase + c * 128 + m;
      #pragma unroll
      for (int qt = 0; qt < 2; ++qt) {
        f32x4 z = {0.f, 0.f, 0.f, 0.f};
        z = __builtin_amdgcn_mfma_f32_16x16x32_bf16(afr[qt][0], b0, z, 0, 0, 0);
        z = __builtin_amdgcn_mfma_f32_16x16x32_bf16(afr[qt][1], b1, z, 0, 0, 0);
        #pragma unroll
        for (int r4 = 0; r4 < 4; ++r4) {
          if (z[r4] > tau_m) {                       // raw dot vs TAU*||K_m||
            int ql = qq0 + qt * 16 + quad * 4 + r4;  // D: row=quad*4+reg (query), col=lane15 (mem)
            u32 p = atomicAdd(&pcnt[ql], 1u);
            if (p < CAP) pidx[(size_t)ql * CAP + p] = (u16)m_g;
          }
        }
      }
    }
    __syncthreads();
  }
  #undef STAGE
}

// ---------- KNN select: fp64 rescore -> per-wave shuffle top-33 -> soft-blend -> fp64 V-sum ----------
__global__ __launch_bounds__(256) void knnB_kernel(
    const u32* __restrict__ pcnt, const u16* __restrict__ pidx,
    const double* __restrict__ QM64, const float* __restrict__ Km,
    const float* __restrict__ Vm, const double* __restrict__ kinv64,
    float* __restrict__ wt)
{
  __shared__ float pool_v[32][CAP];
  __shared__ u16   pool_i[32][CAP];
  __shared__ float out_v[32][34];
  __shared__ u16   out_i[32][34];
  __shared__ int   ncnt[32];
  int t = threadIdx.x;
  int qq0 = blockIdx.x * 32;
  int h2 = qq0 >> 11;
  if (t < 32) ncnt[t] = min((int)pcnt[qq0 + t], CAP);
  __syncthreads();
  // fp64 rescore -> fp32 scores (fp32 ulp ~4e-9 << 1.5e-6 blend width; selection semantics kept)
  for (int slot = t; slot < 32 * CAP; slot += 256) {
    int q = slot / CAP, j = slot - q * CAP;
    if (j < ncnt[q]) {
      int id = pidx[(size_t)(qq0 + q) * CAP + j];
      pool_i[q][j] = (u16)id;
      const double* qv = &QM64[(qq0 + q) * 64];
      const float*  kr = &Km[(size_t)(h2 * 8192 + id) * 64];
      double d0 = 0, d1 = 0, d2 = 0, d3 = 0;
      #pragma unroll
      for (int d = 0; d < 64; d += 4) {
        d0 = fma(qv[d+0], (double)kr[d+0], d0);
        d1 = fma(qv[d+1], (double)kr[d+1], d1);
        d2 = fma(qv[d+2], (double)kr[d+2], d2);
        d3 = fma(qv[d+3], (double)kr[d+3], d3);
      }
      pool_v[q][j] = (float)(((d0 + d1) + (d2 + d3)) * kinv64[h2 * 8192 + id]);
    } else {
      pool_v[q][j] = -1e30f;
      pool_i[q][j] = 0;
    }
  }
  __syncthreads();
  int w = t >> 6, l = t & 63;
  const float* Vmh = Vm + (size_t)h2 * 524288;
  // each wave owns 8 queries: shuffle-argmax top-33 extraction, blend, fp64 V-sum
  for (int qi = 0; qi < 8; ++qi) {
    int q = w * 8 + qi;
    float v0 = pool_v[q][l], v1 = pool_v[q][l + 64], v2 = pool_v[q][l + 128];
    int   i0 = pool_i[q][l], i1 = pool_i[q][l + 64], i2 = pool_i[q][l + 128];
    for (int r = 0; r < 33; ++r) {
      float bv = v0; int bi = i0, bs = 0;
      if (v1 > bv || (v1 == bv && i1 < bi)) { bv = v1; bi = i1; bs = 1; }
      if (v2 > bv || (v2 == bv && i2 < bi)) { bv = v2; bi = i2; bs = 2; }
      float rv = bv; int ri = bi;
      #pragma unroll
      for (int m = 32; m >= 1; m >>= 1) {
        float ov = __shfl_xor(rv, m);
        int   oi = __shfl_xor(ri, m);
        if (ov > rv || (ov == rv && oi < ri)) { rv = ov; ri = oi; }
      }
      if (bv == rv && bi == ri) {     // owning lane retires its slot (indices unique)
        if (bs == 0) v0 = -1e30f; else if (bs == 1) v1 = -1e30f; else v2 = -1e30f;
      }
      if (l == 0) { out_v[q][r] = rv; out_i[q][r] = (u16)ri; }
    }
    if (l == 0) {   // soft-blend rank 32/33 boundary
      float g = out_v[q][31] - out_v[q][32];
      float lam = 0.5f * erfcf(g * 471404.52f);   // 1/(sqrt(2)*1.5e-6)
      out_v[q][31] *= (1.0f - lam);
      out_v[q][32] *= lam;
    }
    double acc = 0.0;
    #pragma unroll 3
    for (int j = 0; j < 33; ++j) {
      float v = out_v[q][j];          // broadcast read (free)
      int  id = out_i[q][j];
      if (v > -1e29f) acc = fma((double)v, (double)Vmh[id * 64 + l], acc);
    }
    wt[(qq0 + q) * 64 + l] = (float)acc;
  }
}

// ---------- gate combine -> [2048, 512] fp32 ----------
__global__ __launch_bounds__(256) void combine_kernel(const float* __restrict__ attn,
    const float* __restrict__ wt, const float* __restrict__ gate, float* __restrict__ comb)
{
  int tid = blockIdx.x * 256 + threadIdx.x;     // < 1048576
  int r = tid >> 9, c = tid & 511;
  int ho = c >> 6, dk = c & 63;
  int bo = r >> 10, s = r & 1023;
  float g = 1.0f / (1.0f + __expf(-gate[ho]));
  float wv = wt[(ho * 2048 + r) * 64 + dk];                  // weighted[ho][bo*1024+s][dk]
  float av = attn[((ho * 2 + bo) * 1024 + s) * 64 + dk];     // attn_out[i_att=ho*2+bo]
  comb[tid] = g * wv + (1.0f - g) * av;
}

extern "C" void kernel_launch(void* const* d_in, const int* in_sizes, int n_in,
                              void* d_out, int out_size, void* d_ws, size_t ws_size,
                              hipStream_t stream) {
  const float* x    = (const float*)d_in[0];
  const float* Wq   = (const float*)d_in[1];
  const float* bq   = (const float*)d_in[2];
  const float* Wk   = (const float*)d_in[3];
  const float* bk   = (const float*)d_in[4];
  const float* Wv   = (const float*)d_in[5];
  const float* bv   = (const float*)d_in[6];
  const float* Wo   = (const float*)d_in[7];
  const float* bo   = (const float*)d_in[8];
  const float* Km   = (const float*)d_in[9];
  const float* Vm   = (const float*)d_in[10];
  const float* gate = (const float*)d_in[11];
  float* out = (float*)d_out;
  float* ws = (float*)d_ws;
  // layout (floats). KB16 overlays WT+COMB; pool overlays Q/K (disjoint lifetimes).
  float*  Q      = ws;                         // [0, 1048576)
  float*  K      = ws + 1048576;               // [1048576, 2097152)
  float*  V      = ws + 2097152;               // [2097152, 3145728)
  float*  ATT    = ws + 3145728;               // [3145728, 4194304)
  float*  WT     = ws + 4194304;               // [4194304, 5242880)  (after knnA)
  float*  COMB   = ws + 5242880;               // [5242880, 6291456)  (after knnB)
  u16*    KB16   = (u16*)(ws + 4194304);       // 8.39 MB, lifetime kcvt..knnA
  float*  QM32   = ws + 6291456;               // 1048576
  float*  TAU32  = ws + 7340032;               // 65536
  double* QM64   = (double*)(ws + 7405568);    // 1048576 doubles
  double* KINV64 = (double*)(ws + 9502720);    // 65536 doubles
  u32*    PCNT   = (u32*)ws;                   // 16384 u32, lifetime post-attn (over Q)
  u16*    PIDX   = (u16*)(ws + 16384);         // 16384*CAP u16 (over Q/K)
  gemm_qkv<<<dim3(8, 32, 3), 256, 0, stream>>>(x, Wq, bq, Wk, bk, Wv, bv, Q, K, V);
  qmem64_kernel<<<dim3(512), 256, 0, stream>>>(x, Wq, bq, QM64, QM32);
  kprep_kernel<<<dim3(256), 256, 0, stream>>>(Km, KINV64, TAU32);
  kcvt_kernel<<<dim3(2048), 256, 0, stream>>>(Km, (u32*)KB16);
  attn_kernel<<<dim3(256, 16), 256, 0, stream>>>(Q, K, V, ATT);
  hipMemsetAsync(PCNT, 0, 16384 * sizeof(u32), stream);
  knnA_kernel<<<dim3(512, 2), 256, 0, stream>>>(QM32, KB16, TAU32, PCNT, PIDX);
  knnB_kernel<<<dim3(512), 256, 0, stream>>>(PCNT, PIDX, QM64, Km, Vm, KINV64, WT);
  combine_kernel<<<dim3(4096), 256, 0, stream>>>(ATT, WT, gate, COMB);
  gemm_out_k<<<dim3(8, 32), 256, 0, stream>>>(COMB, Wo, bo, out);
}

// Round 8
// 832.180 us; speedup vs baseline: 1.9038x; 1.1474x over previous
//
#include <hip/hip_runtime.h>
#include <math.h>

typedef unsigned int   u32;
typedef unsigned short u16;
typedef __attribute__((ext_vector_type(8))) short short8;
typedef __attribute__((ext_vector_type(4))) float f32x4;

#define TAUF 0.0350f
#define CAP  192
#define QB   16

__device__ __forceinline__ u16 f2b(float f) {
  u32 u = __float_as_uint(f);
  u += 0x7fffu + ((u >> 16) & 1u);   // RNE
  return (u16)(u >> 16);
}

__device__ __forceinline__ void gload_lds16(const void* g, void* l) {
  __builtin_amdgcn_global_load_lds(
      (const __attribute__((address_space(1))) u32*)g,
      (__attribute__((address_space(3))) u32*)l, 16, 0, 0);
}

#define FMA16 \
  acc[0][0]=fmaf(a4.x,b4.x,acc[0][0]); acc[0][1]=fmaf(a4.x,b4.y,acc[0][1]); \
  acc[0][2]=fmaf(a4.x,b4.z,acc[0][2]); acc[0][3]=fmaf(a4.x,b4.w,acc[0][3]); \
  acc[1][0]=fmaf(a4.y,b4.x,acc[1][0]); acc[1][1]=fmaf(a4.y,b4.y,acc[1][1]); \
  acc[1][2]=fmaf(a4.y,b4.z,acc[1][2]); acc[1][3]=fmaf(a4.y,b4.w,acc[1][3]); \
  acc[2][0]=fmaf(a4.z,b4.x,acc[2][0]); acc[2][1]=fmaf(a4.z,b4.y,acc[2][1]); \
  acc[2][2]=fmaf(a4.z,b4.z,acc[2][2]); acc[2][3]=fmaf(a4.z,b4.w,acc[2][3]); \
  acc[3][0]=fmaf(a4.w,b4.x,acc[3][0]); acc[3][1]=fmaf(a4.w,b4.y,acc[3][1]); \
  acc[3][2]=fmaf(a4.w,b4.z,acc[3][2]); acc[3][3]=fmaf(a4.w,b4.w,acc[3][3]);

// ---------- QKV projection: fp32 C[2048,512] = A @ W[512,512] + b ----------
__global__ __launch_bounds__(256) void gemm_qkv(const float* __restrict__ x,
    const float* __restrict__ Wq, const float* __restrict__ bq,
    const float* __restrict__ Wk, const float* __restrict__ bk,
    const float* __restrict__ Wv, const float* __restrict__ bv,
    float* __restrict__ Qo, float* __restrict__ Ko, float* __restrict__ Vo)
{
  __shared__ float As[16][68];
  __shared__ float Bs[16][68];
  int z = blockIdx.z;
  const float* W    = (z == 0) ? Wq : (z == 1) ? Wk : Wv;
  const float* bias = (z == 0) ? bq : (z == 1) ? bk : bv;
  float*       out  = (z == 0) ? Qo : (z == 1) ? Ko : Vo;
  int t = threadIdx.x;
  int m0 = blockIdx.y * 64, n0 = blockIdx.x * 64;
  int tx = t & 15, ty = t >> 4;
  int am = t >> 2, ak = (t & 3) * 4;
  int bkk = t >> 4, bn = (t & 15) * 4;
  float acc[4][4] = {};
  for (int k0 = 0; k0 < 512; k0 += 16) {
    float4 fa = *(const float4*)&x[(m0 + am) * 512 + k0 + ak];
    float4 fb = *(const float4*)&W[(k0 + bkk) * 512 + n0 + bn];
    As[ak + 0][am] = fa.x; As[ak + 1][am] = fa.y;
    As[ak + 2][am] = fa.z; As[ak + 3][am] = fa.w;
    Bs[bkk][bn + 0] = fb.x; Bs[bkk][bn + 1] = fb.y;
    Bs[bkk][bn + 2] = fb.z; Bs[bkk][bn + 3] = fb.w;
    __syncthreads();
    #pragma unroll
    for (int kk = 0; kk < 16; ++kk) {
      float4 a4 = *(const float4*)&As[kk][ty * 4];
      float4 b4 = *(const float4*)&Bs[kk][tx * 4];
      FMA16
    }
    __syncthreads();
  }
  float bb0 = bias[n0+tx*4+0], bb1 = bias[n0+tx*4+1];
  float bb2 = bias[n0+tx*4+2], bb3 = bias[n0+tx*4+3];
  #pragma unroll
  for (int r = 0; r < 4; ++r) {
    float4 o = { acc[r][0] + bb0, acc[r][1] + bb1, acc[r][2] + bb2, acc[r][3] + bb3 };
    *(float4*)&out[(m0 + ty*4 + r) * 512 + n0 + tx*4] = o;
  }
}

// ---------- output projection: fp32 out = A[2048,512] @ Wo + bo ----------
__global__ __launch_bounds__(256) void gemm_out_k(const float* __restrict__ A,
    const float* __restrict__ W, const float* __restrict__ bias, float* __restrict__ out)
{
  __shared__ float As[16][68];
  __shared__ float Bs[16][68];
  int t = threadIdx.x;
  int m0 = blockIdx.y * 64, n0 = blockIdx.x * 64;
  int tx = t & 15, ty = t >> 4;
  int am = t >> 2, ak = (t & 3) * 4;
  int bkk = t >> 4, bn = (t & 15) * 4;
  float acc[4][4] = {};
  for (int k0 = 0; k0 < 512; k0 += 16) {
    float4 fa = *(const float4*)&A[(m0 + am) * 512 + k0 + ak];
    float4 fb = *(const float4*)&W[(k0 + bkk) * 512 + n0 + bn];
    As[ak + 0][am] = fa.x; As[ak + 1][am] = fa.y;
    As[ak + 2][am] = fa.z; As[ak + 3][am] = fa.w;
    Bs[bkk][bn + 0] = fb.x; Bs[bkk][bn + 1] = fb.y;
    Bs[bkk][bn + 2] = fb.z; Bs[bkk][bn + 3] = fb.w;
    __syncthreads();
    #pragma unroll
    for (int kk = 0; kk < 16; ++kk) {
      float4 a4 = *(const float4*)&As[kk][ty * 4];
      float4 b4 = *(const float4*)&Bs[kk][tx * 4];
      FMA16
    }
    __syncthreads();
  }
  float bb0 = bias[n0+tx*4+0], bb1 = bias[n0+tx*4+1];
  float bb2 = bias[n0+tx*4+2], bb3 = bias[n0+tx*4+3];
  #pragma unroll
  for (int r = 0; r < 4; ++r) {
    float4 o = { acc[r][0] + bb0, acc[r][1] + bb1, acc[r][2] + bb2, acc[r][3] + bb3 };
    *(float4*)&out[(m0 + ty*4 + r) * 512 + n0 + tx*4] = o;
  }
}

// ---------- memory-path q̂ in fp64: QM64/QM32 [16384][64], pre-scaled by 1/((||q||+1e-8)*8) ----------
__global__ __launch_bounds__(256) void qmem64_kernel(const float* __restrict__ x,
    const float* __restrict__ Wq, const float* __restrict__ bq,
    double* __restrict__ QM64, float* __restrict__ QM32)
{
  __shared__ float xs[32][68];
  __shared__ float wsh[64][68];
  __shared__ double psum[32][8];
  __shared__ double scal[32];
  int t = threadIdx.x;
  int qq0 = blockIdx.x * 32;                  // 32 consecutive queries: same (b1,h1), s=s0..s0+31
  int b1 = qq0 >> 13, h1 = (qq0 >> 10) & 7, s0 = qq0 & 1023;
  int i = h1 * 2 + b1;                        // torch-reshape scramble
  int batch = i >> 3, col0 = (i & 7) * 64;
  int row = t >> 3, cg = (t & 7) * 8;
  double acc[8] = {};
  for (int k0 = 0; k0 < 512; k0 += 64) {
    #pragma unroll
    for (int j = 0; j < 2; ++j) {
      int idx = t + j * 256;
      int r = idx >> 4, c = (idx & 15) * 4;
      float4 f = *(const float4*)&x[(batch * 1024 + s0 + r) * 512 + k0 + c];
      xs[r][c+0] = f.x; xs[r][c+1] = f.y; xs[r][c+2] = f.z; xs[r][c+3] = f.w;
    }
    #pragma unroll
    for (int j = 0; j < 4; ++j) {
      int idx = t + j * 256;
      int r = idx >> 4, c = (idx & 15) * 4;
      float4 f = *(const float4*)&Wq[(k0 + r) * 512 + col0 + c];
      wsh[r][c+0] = f.x; wsh[r][c+1] = f.y; wsh[r][c+2] = f.z; wsh[r][c+3] = f.w;
    }
    __syncthreads();
    for (int kk = 0; kk < 64; ++kk) {
      double xv = (double)xs[row][kk];
      #pragma unroll
      for (int j = 0; j < 8; ++j) acc[j] = fma(xv, (double)wsh[kk][cg + j], acc[j]);
    }
    __syncthreads();
  }
  #pragma unroll
  for (int j = 0; j < 8; ++j) acc[j] += (double)bq[col0 + cg + j];
  double ps = 0.0;
  #pragma unroll
  for (int j = 0; j < 8; ++j) ps = fma(acc[j], acc[j], ps);
  psum[row][t & 7] = ps;
  __syncthreads();
  if (t < 32) {
    double s = 0.0;
    #pragma unroll
    for (int j = 0; j < 8; ++j) s += psum[t][j];
    scal[t] = 1.0 / ((sqrt(s) + 1e-8) * 8.0);
  }
  __syncthreads();
  double sc = scal[row];
  #pragma unroll
  for (int j = 0; j < 8; ++j) {
    double v = acc[j] * sc;
    QM64[(qq0 + row) * 64 + cg + j] = v;
    QM32[(qq0 + row) * 64 + cg + j] = (float)v;
  }
}

// ---------- per-memory fp64 norm: kinv64 + raw-dot threshold tau32 = TAU*(||K||+1e-8) ----------
__global__ __launch_bounds__(256) void kprep_kernel(const float* __restrict__ Km,
    double* __restrict__ kinv64, float* __restrict__ tau32)
{
  int idx = blockIdx.x * 256 + threadIdx.x;   // 65536
  const float* p = Km + idx * 64;
  double s = 0.0;
  #pragma unroll
  for (int j = 0; j < 16; ++j) {
    float4 f = *(const float4*)&p[j * 4];
    double a = f.x, b = f.y, c = f.z, d = f.w;
    s = fma(a, a, s); s = fma(b, b, s); s = fma(c, c, s); s = fma(d, d, s);
  }
  double nrm = sqrt(s) + 1e-8;
  kinv64[idx] = 1.0 / nrm;
  tau32[idx] = (float)((double)TAUF * nrm);
}

// ---------- Km -> bf16 (once): KB16[65536*64] ----------
__global__ __launch_bounds__(256) void kcvt_kernel(const float* __restrict__ Km,
                                                   u32* __restrict__ KB)
{
  int o = blockIdx.x * 256 + threadIdx.x;     // 524288 threads x 8 floats
  float4 f0 = *(const float4*)&Km[o * 8];
  float4 f1 = *(const float4*)&Km[o * 8 + 4];
  uint4 u;
  u.x = ((u32)f2b(f0.y) << 16) | f2b(f0.x);
  u.y = ((u32)f2b(f0.w) << 16) | f2b(f0.z);
  u.z = ((u32)f2b(f1.y) << 16) | f2b(f1.x);
  u.w = ((u32)f2b(f1.w) << 16) | f2b(f1.z);
  *(uint4*)&KB[o * 4] = u;
}

// ---------- causal attention: 4 query rows per block, batch-head i = blockIdx.y ----------
__global__ __launch_bounds__(256) void attn_kernel(const float* __restrict__ Qb,
    const float* __restrict__ Kb, const float* __restrict__ Vb, float* __restrict__ attn)
{
  __shared__ float qs[4][64];
  __shared__ float Kc[64][65];
  __shared__ float sl[4][1024];
  int bi = blockIdx.y;               // i = borig*8 + horig
  int sq0 = blockIdx.x * 4;
  int borig = bi >> 3, horig = bi & 7;
  int t = threadIdx.x;
  int base = borig * 524288 + horig * 64;
  int w = t >> 6, l = t & 63;
  qs[w][l] = Qb[base + (sq0 + w) * 512 + l];
  __syncthreads();
  int nk = sq0 + 4;
  for (int k0 = 0; k0 < nk; k0 += 64) {
    #pragma unroll
    for (int j = 0; j < 4; ++j) {
      int idx = t + j * 256;
      int key = idx >> 4, f = idx & 15;
      if (k0 + key < nk) {
        float4 kv = *(const float4*)&Kb[base + (k0 + key) * 512 + f * 4];
        Kc[key][f*4+0] = kv.x; Kc[key][f*4+1] = kv.y;
        Kc[key][f*4+2] = kv.z; Kc[key][f*4+3] = kv.w;
      }
    }
    __syncthreads();
    int key = k0 + l;
    if (key <= sq0 + w) {
      float dv = 0.f;
      #pragma unroll
      for (int d = 0; d < 64; ++d) dv = fmaf(qs[w][d], Kc[l][d], dv);
      sl[w][key] = dv * 0.125f;
    }
    __syncthreads();
  }
  int nkr = sq0 + w + 1;
  float mx = -__builtin_inff();
  for (int k = l; k < nkr; k += 64) mx = fmaxf(mx, sl[w][k]);
  #pragma unroll
  for (int msk = 32; msk >= 1; msk >>= 1) mx = fmaxf(mx, __shfl_xor(mx, msk));
  float sum = 0.f;
  for (int k = l; k < nkr; k += 64) { float p = __expf(sl[w][k] - mx); sl[w][k] = p; sum += p; }
  #pragma unroll
  for (int msk = 32; msk >= 1; msk >>= 1) sum += __shfl_xor(sum, msk);
  float inv = 1.0f / sum;
  __syncthreads();
  float acc = 0.f;
  const float* vp = &Vb[base + l];
  #pragma unroll 4
  for (int k = 0; k < nkr; ++k) acc = fmaf(sl[w][k], vp[k * 512], acc);
  attn[(bi * 1024 + sq0 + w) * 64 + l] = acc * inv;
}

// ---------- KNN filter: bf16 MFMA raw dots vs per-memory tau -> global candidate pool ----------
// grid (512 qtiles, 2 mem-shards); head = blockIdx.x & 7 (XCD-clustered); dbuf async staging
__global__ __launch_bounds__(256) void knnA_kernel(
    const float* __restrict__ QM32, const u16* __restrict__ KB16,
    const float* __restrict__ tau32, u32* __restrict__ pcnt, u16* __restrict__ pidx)
{
  __shared__ u16   Kc[2][128 * 64];
  __shared__ float tauc[2][128];
  int t = threadIdx.x;
  int l = t & 63, w = t >> 6;
  int lane15 = l & 15, quad = l >> 4;
  int bidx = blockIdx.x;
  int h2  = bidx & 7;                         // head -> XCD cluster
  int qq0 = (h2 << 11) | ((bidx >> 3) << 5);
  int mbase = blockIdx.y * 4096;              // shard
  const u16* KBh = KB16 + (size_t)(h2 * 8192) * 64;
  const float* tauh = tau32 + h2 * 8192;
  // A-frags: q̂ rows (bf16), resident in VGPRs
  short8 afr[2][2];
  #pragma unroll
  for (int qt = 0; qt < 2; ++qt) {
    int q = qq0 + qt * 16 + lane15;
    #pragma unroll
    for (int kh = 0; kh < 2; ++kh) {
      const float* qp = &QM32[q * 64 + kh * 32 + quad * 8];
      float4 fa = *(const float4*)qp;
      float4 fb = *(const float4*)(qp + 4);
      short8 a;
      a[0]=(short)f2b(fa.x); a[1]=(short)f2b(fa.y); a[2]=(short)f2b(fa.z); a[3]=(short)f2b(fa.w);
      a[4]=(short)f2b(fb.x); a[5]=(short)f2b(fb.y); a[6]=(short)f2b(fb.z); a[7]=(short)f2b(fb.w);
      afr[qt][kh] = a;
    }
  }
  // --- staging helper (async): chunk c of this shard into buffer buf ---
  #define STAGE(buf, c) do { \
    int m0s = mbase + (c) * 128; \
    _Pragma("unroll") \
    for (int i2 = 0; i2 < 4; ++i2) { \
      int slot = i2 * 256 + t; \
      int mm = slot >> 3, gs = slot & 7; \
      int gsrc = gs ^ (mm & 7); \
      gload_lds16(KBh + (size_t)(m0s + mm) * 64 + gsrc * 8, \
                  &Kc[buf][(size_t)(i2 * 256 + (t & ~63)) * 8]); \
    } \
    if (t < 32) gload_lds16(&tauh[m0s + t * 4], &tauc[buf][0]); \
  } while (0)

  STAGE(0, 0);
  __syncthreads();
  for (int c = 0; c < 32; ++c) {
    int cur = c & 1;
    if (c + 1 < 32) STAGE(cur ^ 1, c + 1);
    #pragma unroll
    for (int mi = 0; mi < 2; ++mi) {
      int mt = 2 * w + mi;
      int m = mt * 16 + lane15;
      float tau_m = tauc[cur][m];
      short8 b0 = *(const short8*)&Kc[cur][(m * 8 + (quad       ^ (m & 7))) * 8];
      short8 b1 = *(const short8*)&Kc[cur][(m * 8 + ((4 + quad) ^ (m & 7))) * 8];
      int m_g = mbase + c * 128 + m;
      #pragma unroll
      for (int qt = 0; qt < 2; ++qt) {
        f32x4 z = {0.f, 0.f, 0.f, 0.f};
        z = __builtin_amdgcn_mfma_f32_16x16x32_bf16(afr[qt][0], b0, z, 0, 0, 0);
        z = __builtin_amdgcn_mfma_f32_16x16x32_bf16(afr[qt][1], b1, z, 0, 0, 0);
        #pragma unroll
        for (int r4 = 0; r4 < 4; ++r4) {
          if (z[r4] > tau_m) {                       // raw dot vs TAU*||K_m||
            int ql = qq0 + qt * 16 + quad * 4 + r4;  // D: row=quad*4+reg (query), col=lane15 (mem)
            u32 p = atomicAdd(&pcnt[ql], 1u);
            if (p < CAP) pidx[(size_t)ql * CAP + p] = (u16)m_g;
          }
        }
      }
    }
    __syncthreads();
  }
  #undef STAGE
}

// ---------- KNN select: fp64 rescore -> per-wave shuffle top-33 -> soft-blend -> fp64 V-sum ----------
// 1024 blocks x 16 queries; head = blockIdx & 7 (XCD-clustered: Km[h]+Vm[h] = 4 MB = one L2)
__global__ __launch_bounds__(256) void knnB_kernel(
    const u32* __restrict__ pcnt, const u16* __restrict__ pidx,
    const double* __restrict__ QM64, const float* __restrict__ Km,
    const float* __restrict__ Vm, const double* __restrict__ kinv64,
    float* __restrict__ wt)
{
  __shared__ float pool_v[QB][CAP];
  __shared__ u16   pool_i[QB][CAP];
  __shared__ float out_v[QB][34];
  __shared__ u16   out_i[QB][34];
  __shared__ int   ncnt[QB];
  int t = threadIdx.x;
  int bid = blockIdx.x;
  int h2  = bid & 7;
  int qq0 = (h2 << 11) | ((bid >> 3) << 4);
  if (t < QB) ncnt[t] = min((int)pcnt[qq0 + t], CAP);
  __syncthreads();
  // fp64 rescore -> fp32 scores (fp32 ulp ~4e-9 << 1.5e-6 blend width; selection semantics kept)
  for (int slot = t; slot < QB * CAP; slot += 256) {
    int q = slot / CAP, j = slot - q * CAP;
    if (j < ncnt[q]) {
      int id = pidx[(size_t)(qq0 + q) * CAP + j];
      pool_i[q][j] = (u16)id;
      const double* qv = &QM64[(qq0 + q) * 64];
      const float*  kr = &Km[(size_t)(h2 * 8192 + id) * 64];
      double d0 = 0, d1 = 0, d2 = 0, d3 = 0;
      #pragma unroll
      for (int d = 0; d < 64; d += 4) {
        float4 kf = *(const float4*)&kr[d];
        d0 = fma(qv[d+0], (double)kf.x, d0);
        d1 = fma(qv[d+1], (double)kf.y, d1);
        d2 = fma(qv[d+2], (double)kf.z, d2);
        d3 = fma(qv[d+3], (double)kf.w, d3);
      }
      pool_v[q][j] = (float)(((d0 + d1) + (d2 + d3)) * kinv64[h2 * 8192 + id]);
    } else {
      pool_v[q][j] = -1e30f;
      pool_i[q][j] = 0;
    }
  }
  __syncthreads();
  int w = t >> 6, l = t & 63;
  const float* Vmh = Vm + (size_t)h2 * 524288;
  // each wave owns 4 queries: shuffle-argmax top-33 extraction, blend, fp64 V-sum
  for (int qi = 0; qi < 4; ++qi) {
    int q = w * 4 + qi;
    float v0 = pool_v[q][l], v1 = pool_v[q][l + 64], v2 = pool_v[q][l + 128];
    int   i0 = pool_i[q][l], i1 = pool_i[q][l + 64], i2 = pool_i[q][l + 128];
    for (int r = 0; r < 33; ++r) {
      float bv = v0; int bi = i0, bs = 0;
      if (v1 > bv || (v1 == bv && i1 < bi)) { bv = v1; bi = i1; bs = 1; }
      if (v2 > bv || (v2 == bv && i2 < bi)) { bv = v2; bi = i2; bs = 2; }
      float rv = bv; int ri = bi;
      #pragma unroll
      for (int m = 32; m >= 1; m >>= 1) {
        float ov = __shfl_xor(rv, m);
        int   oi = __shfl_xor(ri, m);
        if (ov > rv || (ov == rv && oi < ri)) { rv = ov; ri = oi; }
      }
      if (bv == rv && bi == ri) {     // owning lane retires its slot (indices unique)
        if (bs == 0) v0 = -1e30f; else if (bs == 1) v1 = -1e30f; else v2 = -1e30f;
      }
      if (l == 0) { out_v[q][r] = rv; out_i[q][r] = (u16)ri; }
    }
    if (l == 0) {   // soft-blend rank 32/33 boundary
      float g = out_v[q][31] - out_v[q][32];
      float lam = 0.5f * erfcf(g * 471404.52f);   // 1/(sqrt(2)*1.5e-6)
      out_v[q][31] *= (1.0f - lam);
      out_v[q][32] *= lam;
    }
    double acc = 0.0;
    #pragma unroll 3
    for (int j = 0; j < 33; ++j) {
      float v = out_v[q][j];          // broadcast read (free)
      int  id = out_i[q][j];
      if (v > -1e29f) acc = fma((double)v, (double)Vmh[id * 64 + l], acc);
    }
    wt[(qq0 + q) * 64 + l] = (float)acc;
  }
}

// ---------- gate combine -> [2048, 512] fp32 ----------
__global__ __launch_bounds__(256) void combine_kernel(const float* __restrict__ attn,
    const float* __restrict__ wt, const float* __restrict__ gate, float* __restrict__ comb)
{
  int tid = blockIdx.x * 256 + threadIdx.x;     // < 1048576
  int r = tid >> 9, c = tid & 511;
  int ho = c >> 6, dk = c & 63;
  int bo = r >> 10, s = r & 1023;
  float g = 1.0f / (1.0f + __expf(-gate[ho]));
  float wv = wt[(ho * 2048 + r) * 64 + dk];                  // weighted[ho][bo*1024+s][dk]
  float av = attn[((ho * 2 + bo) * 1024 + s) * 64 + dk];     // attn_out[i_att=ho*2+bo]
  comb[tid] = g * wv + (1.0f - g) * av;
}

extern "C" void kernel_launch(void* const* d_in, const int* in_sizes, int n_in,
                              void* d_out, int out_size, void* d_ws, size_t ws_size,
                              hipStream_t stream) {
  const float* x    = (const float*)d_in[0];
  const float* Wq   = (const float*)d_in[1];
  const float* bq   = (const float*)d_in[2];
  const float* Wk   = (const float*)d_in[3];
  const float* bk   = (const float*)d_in[4];
  const float* Wv   = (const float*)d_in[5];
  const float* bv   = (const float*)d_in[6];
  const float* Wo   = (const float*)d_in[7];
  const float* bo   = (const float*)d_in[8];
  const float* Km   = (const float*)d_in[9];
  const float* Vm   = (const float*)d_in[10];
  const float* gate = (const float*)d_in[11];
  float* out = (float*)d_out;
  float* ws = (float*)d_ws;
  // layout (floats). KB16 overlays WT+COMB; pool overlays Q/K (disjoint lifetimes).
  float*  Q      = ws;                         // [0, 1048576)
  float*  K      = ws + 1048576;               // [1048576, 2097152)
  float*  V      = ws + 2097152;               // [2097152, 3145728)
  float*  ATT    = ws + 3145728;               // [3145728, 4194304)
  float*  WT     = ws + 4194304;               // [4194304, 5242880)  (after knnA)
  float*  COMB   = ws + 5242880;               // [5242880, 6291456)  (after knnB)
  u16*    KB16   = (u16*)(ws + 4194304);       // 8.39 MB, lifetime kcvt..knnA
  float*  QM32   = ws + 6291456;               // 1048576
  float*  TAU32  = ws + 7340032;               // 65536
  double* QM64   = (double*)(ws + 7405568);    // 1048576 doubles
  double* KINV64 = (double*)(ws + 9502720);    // 65536 doubles
  u32*    PCNT   = (u32*)ws;                   // 16384 u32, lifetime post-attn (over Q)
  u16*    PIDX   = (u16*)(ws + 16384);         // 16384*CAP u16 (over Q/K)
  gemm_qkv<<<dim3(8, 32, 3), 256, 0, stream>>>(x, Wq, bq, Wk, bk, Wv, bv, Q, K, V);
  qmem64_kernel<<<dim3(512), 256, 0, stream>>>(x, Wq, bq, QM64, QM32);
  kprep_kernel<<<dim3(256), 256, 0, stream>>>(Km, KINV64, TAU32);
  kcvt_kernel<<<dim3(2048), 256, 0, stream>>>(Km, (u32*)KB16);
  attn_kernel<<<dim3(256, 16), 256, 0, stream>>>(Q, K, V, ATT);
  hipMemsetAsync(PCNT, 0, 16384 * sizeof(u32), stream);
  knnA_kernel<<<dim3(512, 2), 256, 0, stream>>>(QM32, KB16, TAU32, PCNT, PIDX);
  knnB_kernel<<<dim3(1024), 256, 0, stream>>>(PCNT, PIDX, QM64, Km, Vm, KINV64, WT);
  combine_kernel<<<dim3(4096), 256, 0, stream>>>(ATT, WT, gate, COMB);
  gemm_out_k<<<dim3(8, 32), 256, 0, stream>>>(COMB, Wo, bo, out);
}

// Round 9
// 808.286 us; speedup vs baseline: 1.9601x; 1.0296x over previous
//
#include <hip/hip_runtime.h>
#include <math.h>

typedef unsigned int   u32;
typedef unsigned short u16;
typedef __attribute__((ext_vector_type(8))) short short8;
typedef __attribute__((ext_vector_type(4))) float f32x4;

#define TAUF 0.0350f
#define CAP  192
#define QB2  8

__device__ __forceinline__ u16 f2b(float f) {
  u32 u = __float_as_uint(f);
  u += 0x7fffu + ((u >> 16) & 1u);   // RNE
  return (u16)(u >> 16);
}

__device__ __forceinline__ void gload_lds16(const void* g, void* l) {
  __builtin_amdgcn_global_load_lds(
      (const __attribute__((address_space(1))) u32*)g,
      (__attribute__((address_space(3))) u32*)l, 16, 0, 0);
}

#define FMA16 \
  acc[0][0]=fmaf(a4.x,b4.x,acc[0][0]); acc[0][1]=fmaf(a4.x,b4.y,acc[0][1]); \
  acc[0][2]=fmaf(a4.x,b4.z,acc[0][2]); acc[0][3]=fmaf(a4.x,b4.w,acc[0][3]); \
  acc[1][0]=fmaf(a4.y,b4.x,acc[1][0]); acc[1][1]=fmaf(a4.y,b4.y,acc[1][1]); \
  acc[1][2]=fmaf(a4.y,b4.z,acc[1][2]); acc[1][3]=fmaf(a4.y,b4.w,acc[1][3]); \
  acc[2][0]=fmaf(a4.z,b4.x,acc[2][0]); acc[2][1]=fmaf(a4.z,b4.y,acc[2][1]); \
  acc[2][2]=fmaf(a4.z,b4.z,acc[2][2]); acc[2][3]=fmaf(a4.z,b4.w,acc[2][3]); \
  acc[3][0]=fmaf(a4.w,b4.x,acc[3][0]); acc[3][1]=fmaf(a4.w,b4.y,acc[3][1]); \
  acc[3][2]=fmaf(a4.w,b4.z,acc[3][2]); acc[3][3]=fmaf(a4.w,b4.w,acc[3][3]);

// ---------- QKV projection: fp32 C[2048,512] = A @ W[512,512] + b ----------
__global__ __launch_bounds__(256) void gemm_qkv(const float* __restrict__ x,
    const float* __restrict__ Wq, const float* __restrict__ bq,
    const float* __restrict__ Wk, const float* __restrict__ bk,
    const float* __restrict__ Wv, const float* __restrict__ bv,
    float* __restrict__ Qo, float* __restrict__ Ko, float* __restrict__ Vo)
{
  __shared__ float As[16][68];
  __shared__ float Bs[16][68];
  int z = blockIdx.z;
  const float* W    = (z == 0) ? Wq : (z == 1) ? Wk : Wv;
  const float* bias = (z == 0) ? bq : (z == 1) ? bk : bv;
  float*       out  = (z == 0) ? Qo : (z == 1) ? Ko : Vo;
  int t = threadIdx.x;
  int m0 = blockIdx.y * 64, n0 = blockIdx.x * 64;
  int tx = t & 15, ty = t >> 4;
  int am = t >> 2, ak = (t & 3) * 4;
  int bkk = t >> 4, bn = (t & 15) * 4;
  float acc[4][4] = {};
  for (int k0 = 0; k0 < 512; k0 += 16) {
    float4 fa = *(const float4*)&x[(m0 + am) * 512 + k0 + ak];
    float4 fb = *(const float4*)&W[(k0 + bkk) * 512 + n0 + bn];
    As[ak + 0][am] = fa.x; As[ak + 1][am] = fa.y;
    As[ak + 2][am] = fa.z; As[ak + 3][am] = fa.w;
    Bs[bkk][bn + 0] = fb.x; Bs[bkk][bn + 1] = fb.y;
    Bs[bkk][bn + 2] = fb.z; Bs[bkk][bn + 3] = fb.w;
    __syncthreads();
    #pragma unroll
    for (int kk = 0; kk < 16; ++kk) {
      float4 a4 = *(const float4*)&As[kk][ty * 4];
      float4 b4 = *(const float4*)&Bs[kk][tx * 4];
      FMA16
    }
    __syncthreads();
  }
  float bb0 = bias[n0+tx*4+0], bb1 = bias[n0+tx*4+1];
  float bb2 = bias[n0+tx*4+2], bb3 = bias[n0+tx*4+3];
  #pragma unroll
  for (int r = 0; r < 4; ++r) {
    float4 o = { acc[r][0] + bb0, acc[r][1] + bb1, acc[r][2] + bb2, acc[r][3] + bb3 };
    *(float4*)&out[(m0 + ty*4 + r) * 512 + n0 + tx*4] = o;
  }
}

// ---------- output projection fused with gate-combine:
// out = (g*WT + (1-g)*ATT) @ Wo + bo ----------
__global__ __launch_bounds__(256) void gemm_out_k(const float* __restrict__ ATT,
    const float* __restrict__ WT, const float* __restrict__ gate,
    const float* __restrict__ W, const float* __restrict__ bias, float* __restrict__ out)
{
  __shared__ float As[16][68];
  __shared__ float Bs[16][68];
  __shared__ float gl[8];
  int t = threadIdx.x;
  if (t < 8) gl[t] = 1.0f / (1.0f + __expf(-gate[t]));
  __syncthreads();
  int m0 = blockIdx.y * 64, n0 = blockIdx.x * 64;
  int tx = t & 15, ty = t >> 4;
  int am = t >> 2, ak = (t & 3) * 4;
  int bkk = t >> 4, bn = (t & 15) * 4;
  int r_g = m0 + am;                       // global row
  int bo = r_g >> 10, s = r_g & 1023;
  float acc[4][4] = {};
  for (int k0 = 0; k0 < 512; k0 += 16) {
    int c = k0 + ak;                       // global col in [0,512), c%4==0
    int ho = c >> 6, dk = c & 63;          // float4 never crosses ho boundary
    float4 av = *(const float4*)&ATT[(((ho * 2 + bo) << 10) + s) * 64 + dk];
    float4 wv = *(const float4*)&WT[((ho << 11) + r_g) * 64 + dk];
    float g = gl[ho];
    float4 fb = *(const float4*)&W[(k0 + bkk) * 512 + n0 + bn];
    As[ak + 0][am] = g * wv.x + (1.0f - g) * av.x;
    As[ak + 1][am] = g * wv.y + (1.0f - g) * av.y;
    As[ak + 2][am] = g * wv.z + (1.0f - g) * av.z;
    As[ak + 3][am] = g * wv.w + (1.0f - g) * av.w;
    Bs[bkk][bn + 0] = fb.x; Bs[bkk][bn + 1] = fb.y;
    Bs[bkk][bn + 2] = fb.z; Bs[bkk][bn + 3] = fb.w;
    __syncthreads();
    #pragma unroll
    for (int kk = 0; kk < 16; ++kk) {
      float4 a4 = *(const float4*)&As[kk][ty * 4];
      float4 b4 = *(const float4*)&Bs[kk][tx * 4];
      FMA16
    }
    __syncthreads();
  }
  float bb0 = bias[n0+tx*4+0], bb1 = bias[n0+tx*4+1];
  float bb2 = bias[n0+tx*4+2], bb3 = bias[n0+tx*4+3];
  #pragma unroll
  for (int r = 0; r < 4; ++r) {
    float4 o = { acc[r][0] + bb0, acc[r][1] + bb1, acc[r][2] + bb2, acc[r][3] + bb3 };
    *(float4*)&out[(m0 + ty*4 + r) * 512 + n0 + tx*4] = o;
  }
}

// ---------- memory-path q̂ in fp64: QM64/QM32 [16384][64], pre-scaled by 1/((||q||+1e-8)*8) ----------
__global__ __launch_bounds__(256) void qmem64_kernel(const float* __restrict__ x,
    const float* __restrict__ Wq, const float* __restrict__ bq,
    double* __restrict__ QM64, float* __restrict__ QM32)
{
  __shared__ float xs[32][68];
  __shared__ float wsh[64][68];
  __shared__ double psum[32][8];
  __shared__ double scal[32];
  int t = threadIdx.x;
  int qq0 = blockIdx.x * 32;                  // 32 consecutive queries: same (b1,h1), s=s0..s0+31
  int b1 = qq0 >> 13, h1 = (qq0 >> 10) & 7, s0 = qq0 & 1023;
  int i = h1 * 2 + b1;                        // torch-reshape scramble
  int batch = i >> 3, col0 = (i & 7) * 64;
  int row = t >> 3, cg = (t & 7) * 8;
  double acc[8] = {};
  for (int k0 = 0; k0 < 512; k0 += 64) {
    #pragma unroll
    for (int j = 0; j < 2; ++j) {
      int idx = t + j * 256;
      int r = idx >> 4, c = (idx & 15) * 4;
      float4 f = *(const float4*)&x[(batch * 1024 + s0 + r) * 512 + k0 + c];
      xs[r][c+0] = f.x; xs[r][c+1] = f.y; xs[r][c+2] = f.z; xs[r][c+3] = f.w;
    }
    #pragma unroll
    for (int j = 0; j < 4; ++j) {
      int idx = t + j * 256;
      int r = idx >> 4, c = (idx & 15) * 4;
      float4 f = *(const float4*)&Wq[(k0 + r) * 512 + col0 + c];
      wsh[r][c+0] = f.x; wsh[r][c+1] = f.y; wsh[r][c+2] = f.z; wsh[r][c+3] = f.w;
    }
    __syncthreads();
    for (int kk = 0; kk < 64; ++kk) {
      double xv = (double)xs[row][kk];
      #pragma unroll
      for (int j = 0; j < 8; ++j) acc[j] = fma(xv, (double)wsh[kk][cg + j], acc[j]);
    }
    __syncthreads();
  }
  #pragma unroll
  for (int j = 0; j < 8; ++j) acc[j] += (double)bq[col0 + cg + j];
  double ps = 0.0;
  #pragma unroll
  for (int j = 0; j < 8; ++j) ps = fma(acc[j], acc[j], ps);
  psum[row][t & 7] = ps;
  __syncthreads();
  if (t < 32) {
    double s = 0.0;
    #pragma unroll
    for (int j = 0; j < 8; ++j) s += psum[t][j];
    scal[t] = 1.0 / ((sqrt(s) + 1e-8) * 8.0);
  }
  __syncthreads();
  double sc = scal[row];
  #pragma unroll
  for (int j = 0; j < 8; ++j) {
    double v = acc[j] * sc;
    QM64[(qq0 + row) * 64 + cg + j] = v;
    QM32[(qq0 + row) * 64 + cg + j] = (float)v;
  }
}

// ---------- per-memory fp64 norm: kinv64 + raw-dot threshold tau32 = TAU*(||K||+1e-8) ----------
__global__ __launch_bounds__(256) void kprep_kernel(const float* __restrict__ Km,
    double* __restrict__ kinv64, float* __restrict__ tau32)
{
  int idx = blockIdx.x * 256 + threadIdx.x;   // 65536
  const float* p = Km + idx * 64;
  double s = 0.0;
  #pragma unroll
  for (int j = 0; j < 16; ++j) {
    float4 f = *(const float4*)&p[j * 4];
    double a = f.x, b = f.y, c = f.z, d = f.w;
    s = fma(a, a, s); s = fma(b, b, s); s = fma(c, c, s); s = fma(d, d, s);
  }
  double nrm = sqrt(s) + 1e-8;
  kinv64[idx] = 1.0 / nrm;
  tau32[idx] = (float)((double)TAUF * nrm);
}

// ---------- Km -> bf16 (once): KB16[65536*64] ----------
__global__ __launch_bounds__(256) void kcvt_kernel(const float* __restrict__ Km,
                                                   u32* __restrict__ KB)
{
  int o = blockIdx.x * 256 + threadIdx.x;     // 524288 threads x 8 floats
  float4 f0 = *(const float4*)&Km[o * 8];
  float4 f1 = *(const float4*)&Km[o * 8 + 4];
  uint4 u;
  u.x = ((u32)f2b(f0.y) << 16) | f2b(f0.x);
  u.y = ((u32)f2b(f0.w) << 16) | f2b(f0.z);
  u.z = ((u32)f2b(f1.y) << 16) | f2b(f1.x);
  u.w = ((u32)f2b(f1.w) << 16) | f2b(f1.z);
  *(uint4*)&KB[o * 4] = u;
}

// ---------- causal attention: 4 query rows per block, batch-head i = blockIdx.y ----------
__global__ __launch_bounds__(256) void attn_kernel(const float* __restrict__ Qb,
    const float* __restrict__ Kb, const float* __restrict__ Vb, float* __restrict__ attn)
{
  __shared__ float qs[4][64];
  __shared__ float Kc[64][65];
  __shared__ float sl[4][1024];
  int bi = blockIdx.y;               // i = borig*8 + horig
  int sq0 = blockIdx.x * 4;
  int borig = bi >> 3, horig = bi & 7;
  int t = threadIdx.x;
  int base = borig * 524288 + horig * 64;
  int w = t >> 6, l = t & 63;
  qs[w][l] = Qb[base + (sq0 + w) * 512 + l];
  __syncthreads();
  int nk = sq0 + 4;
  for (int k0 = 0; k0 < nk; k0 += 64) {
    #pragma unroll
    for (int j = 0; j < 4; ++j) {
      int idx = t + j * 256;
      int key = idx >> 4, f = idx & 15;
      if (k0 + key < nk) {
        float4 kv = *(const float4*)&Kb[base + (k0 + key) * 512 + f * 4];
        Kc[key][f*4+0] = kv.x; Kc[key][f*4+1] = kv.y;
        Kc[key][f*4+2] = kv.z; Kc[key][f*4+3] = kv.w;
      }
    }
    __syncthreads();
    int key = k0 + l;
    if (key <= sq0 + w) {
      float dv = 0.f;
      #pragma unroll
      for (int d = 0; d < 64; ++d) dv = fmaf(qs[w][d], Kc[l][d], dv);
      sl[w][key] = dv * 0.125f;
    }
    __syncthreads();
  }
  int nkr = sq0 + w + 1;
  float mx = -__builtin_inff();
  for (int k = l; k < nkr; k += 64) mx = fmaxf(mx, sl[w][k]);
  #pragma unroll
  for (int msk = 32; msk >= 1; msk >>= 1) mx = fmaxf(mx, __shfl_xor(mx, msk));
  float sum = 0.f;
  for (int k = l; k < nkr; k += 64) { float p = __expf(sl[w][k] - mx); sl[w][k] = p; sum += p; }
  #pragma unroll
  for (int msk = 32; msk >= 1; msk >>= 1) sum += __shfl_xor(sum, msk);
  float inv = 1.0f / sum;
  __syncthreads();
  float acc = 0.f;
  const float* vp = &Vb[base + l];
  #pragma unroll 4
  for (int k = 0; k < nkr; ++k) acc = fmaf(sl[w][k], vp[k * 512], acc);
  attn[(bi * 1024 + sq0 + w) * 64 + l] = acc * inv;
}

// ---------- KNN filter: bf16 MFMA raw dots vs per-memory tau -> global candidate pool ----------
// grid (512 qtiles, 2 mem-shards); head = blockIdx.x & 7 (XCD-clustered); dbuf async staging
__global__ __launch_bounds__(256) void knnA_kernel(
    const float* __restrict__ QM32, const u16* __restrict__ KB16,
    const float* __restrict__ tau32, u32* __restrict__ pcnt, u16* __restrict__ pidx)
{
  __shared__ u16   Kc[2][128 * 64];
  __shared__ float tauc[2][128];
  int t = threadIdx.x;
  int l = t & 63, w = t >> 6;
  int lane15 = l & 15, quad = l >> 4;
  int bidx = blockIdx.x;
  int h2  = bidx & 7;                         // head -> XCD cluster
  int qq0 = (h2 << 11) | ((bidx >> 3) << 5);
  int mbase = blockIdx.y * 4096;              // shard
  const u16* KBh = KB16 + (size_t)(h2 * 8192) * 64;
  const float* tauh = tau32 + h2 * 8192;
  // A-frags: q̂ rows (bf16), resident in VGPRs
  short8 afr[2][2];
  #pragma unroll
  for (int qt = 0; qt < 2; ++qt) {
    int q = qq0 + qt * 16 + lane15;
    #pragma unroll
    for (int kh = 0; kh < 2; ++kh) {
      const float* qp = &QM32[q * 64 + kh * 32 + quad * 8];
      float4 fa = *(const float4*)qp;
      float4 fb = *(const float4*)(qp + 4);
      short8 a;
      a[0]=(short)f2b(fa.x); a[1]=(short)f2b(fa.y); a[2]=(short)f2b(fa.z); a[3]=(short)f2b(fa.w);
      a[4]=(short)f2b(fb.x); a[5]=(short)f2b(fb.y); a[6]=(short)f2b(fb.z); a[7]=(short)f2b(fb.w);
      afr[qt][kh] = a;
    }
  }
  // --- staging helper (async): chunk c of this shard into buffer buf ---
  #define STAGE(buf, c) do { \
    int m0s = mbase + (c) * 128; \
    _Pragma("unroll") \
    for (int i2 = 0; i2 < 4; ++i2) { \
      int slot = i2 * 256 + t; \
      int mm = slot >> 3, gs = slot & 7; \
      int gsrc = gs ^ (mm & 7); \
      gload_lds16(KBh + (size_t)(m0s + mm) * 64 + gsrc * 8, \
                  &Kc[buf][(size_t)(i2 * 256 + (t & ~63)) * 8]); \
    } \
    if (t < 32) gload_lds16(&tauh[m0s + t * 4], &tauc[buf][0]); \
  } while (0)

  STAGE(0, 0);
  __syncthreads();
  for (int c = 0; c < 32; ++c) {
    int cur = c & 1;
    if (c + 1 < 32) STAGE(cur ^ 1, c + 1);
    #pragma unroll
    for (int mi = 0; mi < 2; ++mi) {
      int mt = 2 * w + mi;
      int m = mt * 16 + lane15;
      float tau_m = tauc[cur][m];
      short8 b0 = *(const short8*)&Kc[cur][(m * 8 + (quad       ^ (m & 7))) * 8];
      short8 b1 = *(const short8*)&Kc[cur][(m * 8 + ((4 + quad) ^ (m & 7))) * 8];
      int m_g = mbase + c * 128 + m;
      #pragma unroll
      for (int qt = 0; qt < 2; ++qt) {
        f32x4 z = {0.f, 0.f, 0.f, 0.f};
        z = __builtin_amdgcn_mfma_f32_16x16x32_bf16(afr[qt][0], b0, z, 0, 0, 0);
        z = __builtin_amdgcn_mfma_f32_16x16x32_bf16(afr[qt][1], b1, z, 0, 0, 0);
        #pragma unroll
        for (int r4 = 0; r4 < 4; ++r4) {
          if (z[r4] > tau_m) {                       // raw dot vs TAU*||K_m||
            int ql = qq0 + qt * 16 + quad * 4 + r4;  // D: row=quad*4+reg (query), col=lane15 (mem)
            u32 p = atomicAdd(&pcnt[ql], 1u);
            if (p < CAP) pidx[(size_t)ql * CAP + p] = (u16)m_g;
          }
        }
      }
    }
    __syncthreads();
  }
  #undef STAGE
}

// ---------- KNN select: fp64 rescore (2-slot ILP) -> per-wave dual-query shuffle top-33 ----------
// -> soft-blend -> fp64 V-sum.  2048 blocks x 8 queries; head = blockIdx & 7 (XCD-clustered)
__global__ __launch_bounds__(256) void knnB_kernel(
    const u32* __restrict__ pcnt, const u16* __restrict__ pidx,
    const double* __restrict__ QM64, const float* __restrict__ Km,
    const float* __restrict__ Vm, const double* __restrict__ kinv64,
    float* __restrict__ wt)
{
  __shared__ float pool_v[QB2][CAP];
  __shared__ u16   pool_i[QB2][CAP];
  __shared__ float out_v[QB2][34];
  __shared__ u16   out_i[QB2][34];
  __shared__ int   ncnt[QB2];
  int t = threadIdx.x;
  int bid = blockIdx.x;
  int h2  = bid & 7;
  int qq0 = (h2 << 11) | ((bid >> 3) << 3);
  if (t < QB2) ncnt[t] = min((int)pcnt[qq0 + t], CAP);
  __syncthreads();
  // rescore: thread-per-slot, TWO slots in flight (independent fp64 chains + rows)
  // scores bit-identical to prior rounds: 4 partials, ((d0+d1)+(d2+d3)) * kinv64
  #pragma unroll
  for (int base = 0; base < 6; base += 2) {
    int sA = t + base * 256, sB = t + (base + 1) * 256;   // < 1536 = QB2*CAP
    int qA = sA / CAP, jA = sA - qA * CAP;
    int qB = sB / CAP, jB = sB - qB * CAP;
    bool rA = jA < ncnt[qA], rB = jB < ncnt[qB];
    int idA = rA ? (int)pidx[(size_t)(qq0 + qA) * CAP + jA] : 0;
    int idB = rB ? (int)pidx[(size_t)(qq0 + qB) * CAP + jB] : 0;
    const float*  krA = &Km[((size_t)h2 * 8192 + idA) * 64];
    const float*  krB = &Km[((size_t)h2 * 8192 + idB) * 64];
    const double* qvA = &QM64[(qq0 + qA) * 64];
    const double* qvB = &QM64[(qq0 + qB) * 64];
    double a0 = 0, a1 = 0, a2 = 0, a3 = 0;
    double b0 = 0, b1 = 0, b2 = 0, b3 = 0;
    #pragma unroll 8
    for (int d = 0; d < 64; d += 4) {
      float4 kA = *(const float4*)&krA[d];
      float4 kB = *(const float4*)&krB[d];
      a0 = fma(qvA[d+0], (double)kA.x, a0);
      b0 = fma(qvB[d+0], (double)kB.x, b0);
      a1 = fma(qvA[d+1], (double)kA.y, a1);
      b1 = fma(qvB[d+1], (double)kB.y, b1);
      a2 = fma(qvA[d+2], (double)kA.z, a2);
      b2 = fma(qvB[d+2], (double)kB.z, b2);
      a3 = fma(qvA[d+3], (double)kA.w, a3);
      b3 = fma(qvB[d+3], (double)kB.w, b3);
    }
    pool_v[qA][jA] = rA ? (float)(((a0 + a1) + (a2 + a3)) * kinv64[h2 * 8192 + idA]) : -1e30f;
    pool_i[qA][jA] = (u16)idA;
    pool_v[qB][jB] = rB ? (float)(((b0 + b1) + (b2 + b3)) * kinv64[h2 * 8192 + idB]) : -1e30f;
    pool_i[qB][jB] = (u16)idB;
  }
  __syncthreads();
  int w = t >> 6, l = t & 63;
  int qA = 2 * w, qB = 2 * w + 1;
  // dual-query interleaved shuffle-argmax top-33 (indices unique per query)
  float va0 = pool_v[qA][l], va1 = pool_v[qA][l + 64], va2 = pool_v[qA][l + 128];
  int   ia0 = pool_i[qA][l], ia1 = pool_i[qA][l + 64], ia2 = pool_i[qA][l + 128];
  float vb0 = pool_v[qB][l], vb1 = pool_v[qB][l + 64], vb2 = pool_v[qB][l + 128];
  int   ib0 = pool_i[qB][l], ib1 = pool_i[qB][l + 64], ib2 = pool_i[qB][l + 128];
  for (int r = 0; r < 33; ++r) {
    float bvA = va0; int biA = ia0, bsA = 0;
    if (va1 > bvA || (va1 == bvA && ia1 < biA)) { bvA = va1; biA = ia1; bsA = 1; }
    if (va2 > bvA || (va2 == bvA && ia2 < biA)) { bvA = va2; biA = ia2; bsA = 2; }
    float bvB = vb0; int biB = ib0, bsB = 0;
    if (vb1 > bvB || (vb1 == bvB && ib1 < biB)) { bvB = vb1; biB = ib1; bsB = 1; }
    if (vb2 > bvB || (vb2 == bvB && ib2 < biB)) { bvB = vb2; biB = ib2; bsB = 2; }
    float rvA = bvA; int riA = biA;
    float rvB = bvB; int riB = biB;
    #pragma unroll
    for (int m = 32; m >= 1; m >>= 1) {
      float ovA = __shfl_xor(rvA, m); int oiA = __shfl_xor(riA, m);
      float ovB = __shfl_xor(rvB, m); int oiB = __shfl_xor(riB, m);
      if (ovA > rvA || (ovA == rvA && oiA < riA)) { rvA = ovA; riA = oiA; }
      if (ovB > rvB || (ovB == rvB && oiB < riB)) { rvB = ovB; riB = oiB; }
    }
    if (bvA == rvA && biA == riA) {
      if (bsA == 0) va0 = -1e30f; else if (bsA == 1) va1 = -1e30f; else va2 = -1e30f;
    }
    if (bvB == rvB && biB == riB) {
      if (bsB == 0) vb0 = -1e30f; else if (bsB == 1) vb1 = -1e30f; else vb2 = -1e30f;
    }
    if (l == 0) {
      out_v[qA][r] = rvA; out_i[qA][r] = (u16)riA;
      out_v[qB][r] = rvB; out_i[qB][r] = (u16)riB;
    }
  }
  if (l == 0) {   // soft-blend rank 32/33 boundary for both queries
    float gA = out_v[qA][31] - out_v[qA][32];
    float lamA = 0.5f * erfcf(gA * 471404.52f);   // 1/(sqrt(2)*1.5e-6)
    out_v[qA][31] *= (1.0f - lamA);
    out_v[qA][32] *= lamA;
    float gB = out_v[qB][31] - out_v[qB][32];
    float lamB = 0.5f * erfcf(gB * 471404.52f);
    out_v[qB][31] *= (1.0f - lamB);
    out_v[qB][32] *= lamB;
  }
  // fp64 V-sum, both queries interleaved
  const float* Vmh = Vm + (size_t)h2 * 524288;
  double accA = 0.0, accB = 0.0;
  #pragma unroll 3
  for (int j = 0; j < 33; ++j) {
    float vA = out_v[qA][j]; int idA = out_i[qA][j];
    float vB = out_v[qB][j]; int idB = out_i[qB][j];
    if (vA > -1e29f) accA = fma((double)vA, (double)Vmh[idA * 64 + l], accA);
    if (vB > -1e29f) accB = fma((double)vB, (double)Vmh[idB * 64 + l], accB);
  }
  wt[(qq0 + qA) * 64 + l] = (float)accA;
  wt[(qq0 + qB) * 64 + l] = (float)accB;
}

extern "C" void kernel_launch(void* const* d_in, const int* in_sizes, int n_in,
                              void* d_out, int out_size, void* d_ws, size_t ws_size,
                              hipStream_t stream) {
  const float* x    = (const float*)d_in[0];
  const float* Wq   = (const float*)d_in[1];
  const float* bq   = (const float*)d_in[2];
  const float* Wk   = (const float*)d_in[3];
  const float* bk   = (const float*)d_in[4];
  const float* Wv   = (const float*)d_in[5];
  const float* bv   = (const float*)d_in[6];
  const float* Wo   = (const float*)d_in[7];
  const float* bo   = (const float*)d_in[8];
  const float* Km   = (const float*)d_in[9];
  const float* Vm   = (const float*)d_in[10];
  const float* gate = (const float*)d_in[11];
  float* out = (float*)d_out;
  float* ws = (float*)d_ws;
  // layout (floats). KB16 overlays WT region before knnB writes it; pool overlays Q/K.
  float*  Q      = ws;                         // [0, 1048576)
  float*  K      = ws + 1048576;               // [1048576, 2097152)
  float*  V      = ws + 2097152;               // [2097152, 3145728)
  float*  ATT    = ws + 3145728;               // [3145728, 4194304)
  float*  WT     = ws + 4194304;               // [4194304, 5242880)  (written by knnB)
  u16*    KB16   = (u16*)(ws + 4194304);       // 8.39 MB, lifetime kcvt..knnA (before WT write)
  float*  QM32   = ws + 6291456;               // 1048576
  float*  TAU32  = ws + 7340032;               // 65536
  double* QM64   = (double*)(ws + 7405568);    // 1048576 doubles
  double* KINV64 = (double*)(ws + 9502720);    // 65536 doubles
  u32*    PCNT   = (u32*)ws;                   // 16384 u32, lifetime post-attn (over Q)
  u16*    PIDX   = (u16*)(ws + 16384);         // 16384*CAP u16 (over Q/K)
  gemm_qkv<<<dim3(8, 32, 3), 256, 0, stream>>>(x, Wq, bq, Wk, bk, Wv, bv, Q, K, V);
  qmem64_kernel<<<dim3(512), 256, 0, stream>>>(x, Wq, bq, QM64, QM32);
  kprep_kernel<<<dim3(256), 256, 0, stream>>>(Km, KINV64, TAU32);
  kcvt_kernel<<<dim3(2048), 256, 0, stream>>>(Km, (u32*)KB16);
  attn_kernel<<<dim3(256, 16), 256, 0, stream>>>(Q, K, V, ATT);
  hipMemsetAsync(PCNT, 0, 16384 * sizeof(u32), stream);
  knnA_kernel<<<dim3(512, 2), 256, 0, stream>>>(QM32, KB16, TAU32, PCNT, PIDX);
  knnB_kernel<<<dim3(2048), 256, 0, stream>>>(PCNT, PIDX, QM64, Km, Vm, KINV64, WT);
  gemm_out_k<<<dim3(8, 32), 256, 0, stream>>>(ATT, WT, gate, Wo, bo, out);
}